// Round 2
// baseline (4610.405 us; speedup 1.0000x reference)
//
#include <hip/hip_runtime.h>
#include <hip/hip_fp16.h>

// Problem constants (fixed by setup_inputs)
#define E_TOTAL 524288
#define RRELU_SLOPE 0.22916666666666666f

typedef float f32x4 __attribute__((ext_vector_type(4)));
typedef short short8_t __attribute__((ext_vector_type(8)));
typedef _Float16 h2_t __attribute__((ext_vector_type(2)));

#if defined(__has_builtin)
# if __has_builtin(__builtin_amdgcn_fdot2)
#  define HAVE_FDOT2 1
# endif
#endif

__device__ inline unsigned short f2bf(float x) {
  unsigned int u = __float_as_uint(x);
  u += 0x7FFFu + ((u >> 16) & 1u);   // RNE
  return (unsigned short)(u >> 16);
}

__device__ inline unsigned int pack_h2(float a, float b) {
  __half2 h = __floats2half2_rn(a, b);
  return __builtin_bit_cast(unsigned int, h);
}

__device__ inline float dot2f(unsigned int a, unsigned int b, float c) {
#ifdef HAVE_FDOT2
  return __builtin_amdgcn_fdot2(__builtin_bit_cast(h2_t, a),
                                __builtin_bit_cast(h2_t, b), c, false);
#else
  h2_t av = __builtin_bit_cast(h2_t, a);
  h2_t bv = __builtin_bit_cast(h2_t, b);
  return c + (float)av[0] * (float)bv[0] + (float)av[1] * (float)bv[1];
#endif
}

__device__ inline float dot4(float4 a, float4 b) {
  return a.x * b.x + a.y * b.y + a.z * b.z + a.w * b.w;
}

// ---------------------------------------------------------------------------
// Generic bf16-MFMA GEMM: C[M,N] = act(A[M,K](fp32) @ B[K,N] + bias)
// B passed pre-transposed+converted: BT[N][K] bf16. Grid: (M/128, N/128).
// act: 0=none, 1=relu, 2=rrelu
// ---------------------------------------------------------------------------
__global__ __launch_bounds__(256) void gemm_bf16(
    const float* __restrict__ A, int lda,
    const unsigned short* __restrict__ BT,
    const float* __restrict__ bias,
    float* __restrict__ C, int ldc,
    int K, int act)
{
  __shared__ unsigned short As[128][32];
  __shared__ unsigned short Bs[128][32];
  const int tid = threadIdx.x;
  const int bm = blockIdx.x, bn = blockIdx.y;
  const int w = tid >> 6, l = tid & 63;
  const int wm = (w & 1) * 64, wn = (w >> 1) * 64;
  const int q = l >> 4, r = l & 15;

  f32x4 acc[4][4];
  for (int i = 0; i < 4; ++i)
    for (int j = 0; j < 4; ++j)
      acc[i][j] = (f32x4){0.f, 0.f, 0.f, 0.f};

  const int sm = tid >> 1;        // 0..127 (row within tile)
  const int sk = (tid & 1) * 16;  // 0 or 16
  const float* ap = A + (size_t)(bm * 128 + sm) * lda + sk;
  const unsigned short* bp = BT + (size_t)(bn * 128 + sm) * K + sk;

  for (int k0 = 0; k0 < K; k0 += 32) {
    // stage A (fp32 -> bf16)
    float4 f0 = *(const float4*)(ap + k0);
    float4 f1 = *(const float4*)(ap + k0 + 4);
    float4 f2 = *(const float4*)(ap + k0 + 8);
    float4 f3 = *(const float4*)(ap + k0 + 12);
    uint4 p0, p1;
    p0.x = (unsigned)f2bf(f0.x) | ((unsigned)f2bf(f0.y) << 16);
    p0.y = (unsigned)f2bf(f0.z) | ((unsigned)f2bf(f0.w) << 16);
    p0.z = (unsigned)f2bf(f1.x) | ((unsigned)f2bf(f1.y) << 16);
    p0.w = (unsigned)f2bf(f1.z) | ((unsigned)f2bf(f1.w) << 16);
    p1.x = (unsigned)f2bf(f2.x) | ((unsigned)f2bf(f2.y) << 16);
    p1.y = (unsigned)f2bf(f2.z) | ((unsigned)f2bf(f2.w) << 16);
    p1.z = (unsigned)f2bf(f3.x) | ((unsigned)f2bf(f3.y) << 16);
    p1.w = (unsigned)f2bf(f3.z) | ((unsigned)f2bf(f3.w) << 16);
    *(uint4*)&As[sm][sk] = p0;
    *(uint4*)&As[sm][sk + 8] = p1;
    // stage B (already bf16, [n][k] layout)
    uint4 b0 = *(const uint4*)(bp + k0);
    uint4 b1 = *(const uint4*)(bp + k0 + 8);
    *(uint4*)&Bs[sm][sk] = b0;
    *(uint4*)&Bs[sm][sk + 8] = b1;
    __syncthreads();

    short8_t af[4], bfr[4];
    for (int mt = 0; mt < 4; ++mt)
      af[mt] = *(const short8_t*)&As[wm + mt * 16 + r][q * 8];
    for (int nt = 0; nt < 4; ++nt)
      bfr[nt] = *(const short8_t*)&Bs[wn + nt * 16 + r][q * 8];
    for (int mt = 0; mt < 4; ++mt)
      for (int nt = 0; nt < 4; ++nt)
        acc[mt][nt] = __builtin_amdgcn_mfma_f32_16x16x32_bf16(
            af[mt], bfr[nt], acc[mt][nt], 0, 0, 0);
    __syncthreads();
  }

  // epilogue: C/D layout col=l&15, row=(l>>4)*4+reg
  for (int nt = 0; nt < 4; ++nt) {
    int gc = bn * 128 + wn + nt * 16 + r;
    float bv = bias ? bias[gc] : 0.f;
    for (int mt = 0; mt < 4; ++mt) {
      int gm = bm * 128 + wm + mt * 16 + q * 4;
      for (int rr = 0; rr < 4; ++rr) {
        float v = acc[mt][nt][rr] + bv;
        if (act == 1) v = fmaxf(v, 0.f);
        else if (act == 2) v = (v >= 0.f) ? v : v * RRELU_SLOPE;
        C[(size_t)(gm + rr) * ldc + gc] = v;
      }
    }
  }
}

// ---------------------------------------------------------------------------
// Edge message + aggregate + update (v2).
// y[T,512] = [x@Wn+bm | x@Ws+bs]. One block per (graph, dim-half).
// Per-graph y message-slice staged in LDS (32 KB) so the per-edge gather is
// a ds_read, not a dependent global chain. Edge metadata (src,dst,ea)
// prefetched one iteration ahead. launch_bounds(1024,4) -> 128-VGPR budget
// so the 16 We regs + pipeline regs stay resident (round-0 had VGPR=24 and
// ~12.8K cyc/edge from serialized reloads).
// ---------------------------------------------------------------------------
__global__ __launch_bounds__(1024, 4) void edge_conv(
    const float* __restrict__ y,
    const int* __restrict__ eidx,           // [2, E]
    const unsigned int* __restrict__ ea_h2, // [E, 8] half2 pairs
    const unsigned int* __restrict__ We_h2, // [8, 256] half2 (k-pairs)
    float* __restrict__ x_out)
{
  __shared__ float agg[64 * 128];
  __shared__ float ystage[64 * 128];
  const int g = blockIdx.x >> 1;
  const int dbase = (blockIdx.x & 1) * 128;
  const int tid = threadIdx.x;
  // zero agg + stage y message-half for this graph: ystage[n][dd]
  for (int i = tid; i < 8192; i += 1024) {
    agg[i] = 0.f;
    int n = i >> 7, dd = i & 127;
    ystage[i] = y[(size_t)(g * 64 + n) * 512 + dbase + dd];
  }
  const int l = tid & 63;
  const int d0 = dbase + l, d1 = d0 + 64;
  unsigned int we0[8], we1[8];
#pragma unroll
  for (int j = 0; j < 8; ++j) {
    we0[j] = We_h2[j * 256 + d0];
    we1[j] = We_h2[j * 256 + d1];
  }
  __syncthreads();
  const int w = tid >> 6;
  const int ebase = g * 2048 + w * 128;

  // pipeline prologue: edge 0 metadata
  int src = eidx[ebase];
  int dst = eidx[E_TOTAL + ebase];
  uint4 ea0 = *(const uint4*)(ea_h2 + (size_t)ebase * 8);
  uint4 ea1 = *(const uint4*)(ea_h2 + (size_t)ebase * 8 + 4);

  for (int e = 0; e < 128; ++e) {
    int nsrc = 0, ndst = 0;
    uint4 nea0 = {}, nea1 = {};
    if (e < 127) {  // wave-uniform branch
      int ge = ebase + e + 1;
      nsrc = eidx[ge];
      ndst = eidx[E_TOTAL + ge];
      nea0 = *(const uint4*)(ea_h2 + (size_t)ge * 8);
      nea1 = *(const uint4*)(ea_h2 + (size_t)ge * 8 + 4);
    }
    const int sl = src & 63;
    float m0 = ystage[sl * 128 + l];
    float m1 = ystage[sl * 128 + l + 64];
    m0 = dot2f(ea0.x, we0[0], m0); m1 = dot2f(ea0.x, we1[0], m1);
    m0 = dot2f(ea0.y, we0[1], m0); m1 = dot2f(ea0.y, we1[1], m1);
    m0 = dot2f(ea0.z, we0[2], m0); m1 = dot2f(ea0.z, we1[2], m1);
    m0 = dot2f(ea0.w, we0[3], m0); m1 = dot2f(ea0.w, we1[3], m1);
    m0 = dot2f(ea1.x, we0[4], m0); m1 = dot2f(ea1.x, we1[4], m1);
    m0 = dot2f(ea1.y, we0[5], m0); m1 = dot2f(ea1.y, we1[5], m1);
    m0 = dot2f(ea1.z, we0[6], m0); m1 = dot2f(ea1.z, we1[6], m1);
    m0 = dot2f(ea1.w, we0[7], m0); m1 = dot2f(ea1.w, we1[7], m1);
    const int dl = (dst & 63) * 128 + l;
    atomicAdd(&agg[dl], fmaxf(m0, 0.f));
    atomicAdd(&agg[dl + 64], fmaxf(m1, 0.f));
    src = nsrc; dst = ndst; ea0 = nea0; ea1 = nea1;
  }
  __syncthreads();
  for (int i = tid; i < 8192; i += 1024) {
    int n = i >> 7, dd = i & 127;
    float v = y[(size_t)(g * 64 + n) * 512 + 256 + dbase + dd] + agg[i];
    x_out[(size_t)(g * 64 + n) * 256 + dbase + dd] = fmaxf(v, 0.f);
  }
}

// ---------------------------------------------------------------------------
// dot_pool: per graph, item = X1 @ X2^T [64x64]; write max & mean to fusion.
// ---------------------------------------------------------------------------
__global__ __launch_bounds__(256) void dot_pool_k(
    const float* __restrict__ x1, const float* __restrict__ x2,
    float* __restrict__ fusion, int step)
{
  __shared__ float s1[64][68];
  __shared__ float s2[64][68];
  __shared__ float redm[4], reds[4];
  const int g = blockIdx.x;
  const int tid = threadIdx.x;
  const int ti = (tid & 15) * 4;
  const int tj = (tid >> 4) * 4;
  float acc[4][4] = {};
  for (int kc = 0; kc < 256; kc += 64) {
    for (int rr = 0; rr < 4; ++rr) {
      int lin = tid + rr * 256;
      int n = lin >> 4, k4 = (lin & 15) * 4;
      *(float4*)&s1[n][k4] = *(const float4*)(x1 + (size_t)(g * 64 + n) * 256 + kc + k4);
      *(float4*)&s2[n][k4] = *(const float4*)(x2 + (size_t)(g * 64 + n) * 256 + kc + k4);
    }
    __syncthreads();
    for (int kk = 0; kk < 64; kk += 4) {
      float4 a0 = *(const float4*)&s1[ti + 0][kk];
      float4 a1 = *(const float4*)&s1[ti + 1][kk];
      float4 a2 = *(const float4*)&s1[ti + 2][kk];
      float4 a3 = *(const float4*)&s1[ti + 3][kk];
      float4 b0 = *(const float4*)&s2[tj + 0][kk];
      float4 b1 = *(const float4*)&s2[tj + 1][kk];
      float4 b2 = *(const float4*)&s2[tj + 2][kk];
      float4 b3 = *(const float4*)&s2[tj + 3][kk];
      acc[0][0] += dot4(a0, b0); acc[0][1] += dot4(a0, b1);
      acc[0][2] += dot4(a0, b2); acc[0][3] += dot4(a0, b3);
      acc[1][0] += dot4(a1, b0); acc[1][1] += dot4(a1, b1);
      acc[1][2] += dot4(a1, b2); acc[1][3] += dot4(a1, b3);
      acc[2][0] += dot4(a2, b0); acc[2][1] += dot4(a2, b1);
      acc[2][2] += dot4(a2, b2); acc[2][3] += dot4(a2, b3);
      acc[3][0] += dot4(a3, b0); acc[3][1] += dot4(a3, b1);
      acc[3][2] += dot4(a3, b2); acc[3][3] += dot4(a3, b3);
    }
    __syncthreads();
  }
  float mymax = -1e30f, mysum = 0.f;
  for (int i = 0; i < 4; ++i)
    for (int j = 0; j < 4; ++j) {
      mymax = fmaxf(mymax, acc[i][j]);
      mysum += acc[i][j];
    }
  for (int off = 32; off; off >>= 1) {
    mymax = fmaxf(mymax, __shfl_down(mymax, off, 64));
    mysum += __shfl_down(mysum, off, 64);
  }
  if ((tid & 63) == 0) { redm[tid >> 6] = mymax; reds[tid >> 6] = mysum; }
  __syncthreads();
  if (tid == 0) {
    float gm = fmaxf(fmaxf(redm[0], redm[1]), fmaxf(redm[2], redm[3]));
    float gs = reds[0] + reds[1] + reds[2] + reds[3];
    fusion[g * 6 + step * 2] = gm;
    fusion[g * 6 + step * 2 + 1] = gs * (1.f / 4096.f);
  }
}

// ---------------------------------------------------------------------------
// readout: R[g] = [mean(256) | sum(256) | top3-by-last-col rows (3x256)]
// Stable tie-break: strict '>' picks lowest index first (matches stable argsort)
// ---------------------------------------------------------------------------
__global__ __launch_bounds__(256) void readout_assemble(
    const float* __restrict__ xm, float* __restrict__ R)
{
  __shared__ float lastcol[64];
  __shared__ int topi[3];
  const int g = blockIdx.x, d = threadIdx.x;
  float s = 0.f;
  for (int n = 0; n < 64; ++n) s += xm[(size_t)(g * 64 + n) * 256 + d];
  R[(size_t)g * 1280 + d] = s * (1.f / 64.f);
  R[(size_t)g * 1280 + 256 + d] = s;
  if (d < 64) lastcol[d] = xm[(size_t)(g * 64 + d) * 256 + 255];
  __syncthreads();
  if (d == 0) {
    unsigned long long used = 0;
    for (int j = 0; j < 3; ++j) {
      float best = -1e30f;
      int bi = 0;
      for (int n = 0; n < 64; ++n) {
        if ((used >> n) & 1ull) continue;
        if (lastcol[n] > best) { best = lastcol[n]; bi = n; }
      }
      used |= (1ull << bi);
      topi[j] = bi;
    }
  }
  __syncthreads();
  for (int j = 0; j < 3; ++j)
    R[(size_t)g * 1280 + 512 + j * 256 + d] =
        xm[(size_t)(g * 64 + topi[j]) * 256 + d];
}

// ---------------------------------------------------------------------------
// final head: out = (cat(outm1, outm2, fusion) @ Wo1 + bo1) @ Wo2 + bo2
// ---------------------------------------------------------------------------
__global__ __launch_bounds__(256) void final_head(
    const float* __restrict__ outm1, const float* __restrict__ outm2,
    const float* __restrict__ fusion,
    const float* __restrict__ Wo1, const float* __restrict__ bo1,
    const float* __restrict__ Wo2, const float* __restrict__ bo2,
    float* __restrict__ out)
{
  __shared__ float cat[520];
  __shared__ float r0s[4], r1s[4];
  const int g = blockIdx.x, t = threadIdx.x;
  cat[t] = outm1[(size_t)g * 256 + t];
  cat[256 + t] = outm2[(size_t)g * 256 + t];
  if (t < 6) cat[512 + t] = fusion[g * 6 + t];
  __syncthreads();
  float acc = bo1[t];
  for (int k = 0; k < 518; ++k) acc = fmaf(cat[k], Wo1[(size_t)k * 256 + t], acc);
  float p0 = acc * Wo2[t * 2];
  float p1 = acc * Wo2[t * 2 + 1];
  for (int off = 32; off; off >>= 1) {
    p0 += __shfl_down(p0, off, 64);
    p1 += __shfl_down(p1, off, 64);
  }
  if ((t & 63) == 0) { r0s[t >> 6] = p0; r1s[t >> 6] = p1; }
  __syncthreads();
  if (t == 0) {
    out[g * 2] = r0s[0] + r0s[1] + r0s[2] + r0s[3] + bo2[0];
    out[g * 2 + 1] = r1s[0] + r1s[1] + r1s[2] + r1s[3] + bo2[1];
  }
}

// ---------------------------------------------------------------------------
// Prep kernels (run every launch; ws is re-poisoned each call)
// ---------------------------------------------------------------------------
// src [K][256] fp32 -> dst [256][K] bf16. grid = K blocks x 256.
__global__ void transpose_cvt256(const float* __restrict__ src,
                                 unsigned short* __restrict__ dst, int K)
{
  int k = blockIdx.x, n = threadIdx.x;
  dst[n * K + k] = f2bf(src[k * 256 + n]);
}

__global__ void misc_prep(
    const float* bm1, const float* bs1, const float* bm2, const float* bs2,
    const float* We1, const float* We2,
    float* bcat1, float* bcat2,
    unsigned int* weh1, unsigned int* weh2)
{
  int idx = blockIdx.x * 256 + threadIdx.x;  // grid 20 -> 5120
  if (idx < 512) {
    bcat1[idx] = idx < 256 ? bm1[idx] : bs1[idx - 256];
  } else if (idx < 1024) {
    int i = idx - 512;
    bcat2[i] = i < 256 ? bm2[i] : bs2[i - 256];
  } else if (idx < 3072) {
    int i = idx - 1024, j = i >> 8, d = i & 255;
    weh1[i] = pack_h2(We1[(2 * j) * 256 + d], We1[(2 * j + 1) * 256 + d]);
  } else if (idx < 5120) {
    int i = idx - 3072, j = i >> 8, d = i & 255;
    weh2[i] = pack_h2(We2[(2 * j) * 256 + d], We2[(2 * j + 1) * 256 + d]);
  }
}

__global__ void ea_pack(const float* __restrict__ ea1,
                        const float* __restrict__ ea2,
                        unsigned int* __restrict__ d1,
                        unsigned int* __restrict__ d2)
{
  int idx = blockIdx.x * 256 + threadIdx.x;  // grid 32768 -> 2*E*8
  const int n = E_TOTAL * 8;
  const float* s;
  unsigned int* d;
  int r;
  if (idx < n) { s = ea1; d = d1; r = idx; }
  else { s = ea2; d = d2; r = idx - n; }
  int e = r >> 3, j = r & 7;
  float2 v = *(const float2*)(s + (size_t)e * 16 + 2 * j);
  d[r] = pack_h2(v.x, v.y);
}

// ---------------------------------------------------------------------------
extern "C" void kernel_launch(void* const* d_in, const int* in_sizes, int n_in,
                              void* d_out, int out_size, void* d_ws, size_t ws_size,
                              hipStream_t stream)
{
  const float* x1 = (const float*)d_in[0];
  const int* ei1 = (const int*)d_in[1];
  const float* ea1 = (const float*)d_in[2];
  const float* x2 = (const float*)d_in[4];
  const int* ei2 = (const int*)d_in[5];
  const float* ea2 = (const float*)d_in[6];
  const float* W0_1 = (const float*)d_in[8];
  const float* b0_1 = (const float*)d_in[9];
  const float* W0_2 = (const float*)d_in[10];
  const float* b0_2 = (const float*)d_in[11];
  const float* Wn1 = (const float*)d_in[12];
  const float* We1 = (const float*)d_in[13];
  const float* bm1 = (const float*)d_in[14];
  const float* Ws1 = (const float*)d_in[15];
  const float* bs1 = (const float*)d_in[16];
  const float* Wn2 = (const float*)d_in[17];
  const float* We2 = (const float*)d_in[18];
  const float* bm2 = (const float*)d_in[19];
  const float* Ws2 = (const float*)d_in[20];
  const float* bs2 = (const float*)d_in[21];
  const float* Wf1 = (const float*)d_in[22];
  const float* bf1 = (const float*)d_in[23];
  const float* Wf2 = (const float*)d_in[24];
  const float* bf2 = (const float*)d_in[25];
  const float* Wo1 = (const float*)d_in[26];
  const float* bo1 = (const float*)d_in[27];
  const float* Wo2 = (const float*)d_in[28];
  const float* bo2 = (const float*)d_in[29];
  float* out = (float*)d_out;

  float* w = (float*)d_ws;
  size_t off = 0;
  auto alloc = [&](size_t nf) { float* p = w + off; off += nf; return p; };
  float* xmA1 = alloc(4194304);
  float* xmA2 = alloc(4194304);
  float* xmB1 = alloc(4194304);
  float* xmB2 = alloc(4194304);
  float* y1 = alloc(8388608);
  float* y2 = alloc(8388608);
  float* R1 = alloc(327680);
  float* R2 = alloc(327680);
  float* outm1 = alloc(65536);
  float* outm2 = alloc(65536);
  float* fusion = alloc(1536);
  float* bcat1 = alloc(512);
  float* bcat2 = alloc(512);
  unsigned short* W0T1 = (unsigned short*)alloc(16384);
  unsigned short* W0T2 = (unsigned short*)alloc(16384);
  unsigned short* WcT1 = (unsigned short*)alloc(65536);
  unsigned short* WcT2 = (unsigned short*)alloc(65536);
  unsigned short* WfT1 = (unsigned short*)alloc(163840);
  unsigned short* WfT2 = (unsigned short*)alloc(163840);
  unsigned int* weh1 = (unsigned int*)alloc(2048);
  unsigned int* weh2 = (unsigned int*)alloc(2048);
  unsigned int* eah1 = (unsigned int*)alloc(4194304);
  unsigned int* eah2 = (unsigned int*)alloc(4194304);
  (void)in_sizes; (void)n_in; (void)out_size; (void)ws_size;

  // ---- prep ----
  transpose_cvt256<<<128, 256, 0, stream>>>(W0_1, W0T1, 128);
  transpose_cvt256<<<128, 256, 0, stream>>>(W0_2, W0T2, 128);
  transpose_cvt256<<<256, 256, 0, stream>>>(Wn1, WcT1, 256);
  transpose_cvt256<<<256, 256, 0, stream>>>(Ws1, WcT1 + 65536, 256);
  transpose_cvt256<<<256, 256, 0, stream>>>(Wn2, WcT2, 256);
  transpose_cvt256<<<256, 256, 0, stream>>>(Ws2, WcT2 + 65536, 256);
  transpose_cvt256<<<1280, 256, 0, stream>>>(Wf1, WfT1, 1280);
  transpose_cvt256<<<1280, 256, 0, stream>>>(Wf2, WfT2, 1280);
  misc_prep<<<20, 256, 0, stream>>>(bm1, bs1, bm2, bs2, We1, We2,
                                    bcat1, bcat2, weh1, weh2);
  ea_pack<<<32768, 256, 0, stream>>>(ea1, ea2, eah1, eah2);

  // ---- embed: xm = rrelu(x @ W0 + b0) ----
  gemm_bf16<<<dim3(128, 2), 256, 0, stream>>>(x1, 128, W0T1, b0_1, xmA1, 256, 128, 2);
  gemm_bf16<<<dim3(128, 2), 256, 0, stream>>>(x2, 128, W0T2, b0_2, xmA2, 256, 128, 2);

  // ---- 3 message-passing steps ----
  float* cur1 = xmA1; float* cur2 = xmA2;
  float* nxt1 = xmB1; float* nxt2 = xmB2;
  for (int step = 0; step < 3; ++step) {
    gemm_bf16<<<dim3(128, 4), 256, 0, stream>>>(cur1, 256, WcT1, bcat1, y1, 512, 256, 0);
    gemm_bf16<<<dim3(128, 4), 256, 0, stream>>>(cur2, 256, WcT2, bcat2, y2, 512, 256, 0);
    edge_conv<<<512, 1024, 0, stream>>>(y1, ei1, eah1, weh1, nxt1);
    edge_conv<<<512, 1024, 0, stream>>>(y2, ei2, eah2, weh2, nxt2);
    dot_pool_k<<<256, 256, 0, stream>>>(nxt1, nxt2, fusion, step);
    float* t1 = cur1; cur1 = nxt1; nxt1 = t1;
    float* t2 = cur2; cur2 = nxt2; nxt2 = t2;
  }

  // ---- readout + head ----
  readout_assemble<<<256, 256, 0, stream>>>(cur1, R1);
  readout_assemble<<<256, 256, 0, stream>>>(cur2, R2);
  gemm_bf16<<<dim3(2, 2), 256, 0, stream>>>(R1, 1280, WfT1, bf1, outm1, 256, 1280, 0);
  gemm_bf16<<<dim3(2, 2), 256, 0, stream>>>(R2, 1280, WfT2, bf2, outm2, 256, 1280, 0);
  final_head<<<256, 256, 0, stream>>>(outm1, outm2, fusion,
                                      Wo1, bo1, Wo2, bo2, out);
}

// Round 3
// 4601.057 us; speedup vs baseline: 1.0020x; 1.0020x over previous
//
#include <hip/hip_runtime.h>
#include <hip/hip_fp16.h>

// Problem constants (fixed by setup_inputs)
#define E_TOTAL 524288
#define RRELU_SLOPE 0.22916666666666666f

typedef float f32x4 __attribute__((ext_vector_type(4)));
typedef short short8_t __attribute__((ext_vector_type(8)));
typedef _Float16 h2_t __attribute__((ext_vector_type(2)));

#if defined(__has_builtin)
# if __has_builtin(__builtin_amdgcn_fdot2)
#  define HAVE_FDOT2 1
# endif
#endif

__device__ inline unsigned short f2bf(float x) {
  unsigned int u = __float_as_uint(x);
  u += 0x7FFFu + ((u >> 16) & 1u);   // RNE
  return (unsigned short)(u >> 16);
}

__device__ inline unsigned int pack_h2(float a, float b) {
  __half2 h = __floats2half2_rn(a, b);
  return __builtin_bit_cast(unsigned int, h);
}

__device__ inline float dot2f(unsigned int a, unsigned int b, float c) {
#ifdef HAVE_FDOT2
  return __builtin_amdgcn_fdot2(__builtin_bit_cast(h2_t, a),
                                __builtin_bit_cast(h2_t, b), c, false);
#else
  h2_t av = __builtin_bit_cast(h2_t, a);
  h2_t bv = __builtin_bit_cast(h2_t, b);
  return c + (float)av[0] * (float)bv[0] + (float)av[1] * (float)bv[1];
#endif
}

__device__ inline float dot4(float4 a, float4 b) {
  return a.x * b.x + a.y * b.y + a.z * b.z + a.w * b.w;
}

// ---------------------------------------------------------------------------
// Generic bf16-MFMA GEMM: C[M,N] = act(A[M,K](fp32) @ B[K,N] + bias)
// B passed pre-transposed+converted: BT[N][K] bf16. Grid: (M/128, N/128).
// act: 0=none, 1=relu, 2=rrelu
// ---------------------------------------------------------------------------
__global__ __launch_bounds__(256) void gemm_bf16(
    const float* __restrict__ A, int lda,
    const unsigned short* __restrict__ BT,
    const float* __restrict__ bias,
    float* __restrict__ C, int ldc,
    int K, int act)
{
  __shared__ unsigned short As[128][32];
  __shared__ unsigned short Bs[128][32];
  const int tid = threadIdx.x;
  const int bm = blockIdx.x, bn = blockIdx.y;
  const int w = tid >> 6, l = tid & 63;
  const int wm = (w & 1) * 64, wn = (w >> 1) * 64;
  const int q = l >> 4, r = l & 15;

  f32x4 acc[4][4];
  for (int i = 0; i < 4; ++i)
    for (int j = 0; j < 4; ++j)
      acc[i][j] = (f32x4){0.f, 0.f, 0.f, 0.f};

  const int sm = tid >> 1;        // 0..127 (row within tile)
  const int sk = (tid & 1) * 16;  // 0 or 16
  const float* ap = A + (size_t)(bm * 128 + sm) * lda + sk;
  const unsigned short* bp = BT + (size_t)(bn * 128 + sm) * K + sk;

  for (int k0 = 0; k0 < K; k0 += 32) {
    // stage A (fp32 -> bf16)
    float4 f0 = *(const float4*)(ap + k0);
    float4 f1 = *(const float4*)(ap + k0 + 4);
    float4 f2 = *(const float4*)(ap + k0 + 8);
    float4 f3 = *(const float4*)(ap + k0 + 12);
    uint4 p0, p1;
    p0.x = (unsigned)f2bf(f0.x) | ((unsigned)f2bf(f0.y) << 16);
    p0.y = (unsigned)f2bf(f0.z) | ((unsigned)f2bf(f0.w) << 16);
    p0.z = (unsigned)f2bf(f1.x) | ((unsigned)f2bf(f1.y) << 16);
    p0.w = (unsigned)f2bf(f1.z) | ((unsigned)f2bf(f1.w) << 16);
    p1.x = (unsigned)f2bf(f2.x) | ((unsigned)f2bf(f2.y) << 16);
    p1.y = (unsigned)f2bf(f2.z) | ((unsigned)f2bf(f2.w) << 16);
    p1.z = (unsigned)f2bf(f3.x) | ((unsigned)f2bf(f3.y) << 16);
    p1.w = (unsigned)f2bf(f3.z) | ((unsigned)f2bf(f3.w) << 16);
    *(uint4*)&As[sm][sk] = p0;
    *(uint4*)&As[sm][sk + 8] = p1;
    // stage B (already bf16, [n][k] layout)
    uint4 b0 = *(const uint4*)(bp + k0);
    uint4 b1 = *(const uint4*)(bp + k0 + 8);
    *(uint4*)&Bs[sm][sk] = b0;
    *(uint4*)&Bs[sm][sk + 8] = b1;
    __syncthreads();

    short8_t af[4], bfr[4];
    for (int mt = 0; mt < 4; ++mt)
      af[mt] = *(const short8_t*)&As[wm + mt * 16 + r][q * 8];
    for (int nt = 0; nt < 4; ++nt)
      bfr[nt] = *(const short8_t*)&Bs[wn + nt * 16 + r][q * 8];
    for (int mt = 0; mt < 4; ++mt)
      for (int nt = 0; nt < 4; ++nt)
        acc[mt][nt] = __builtin_amdgcn_mfma_f32_16x16x32_bf16(
            af[mt], bfr[nt], acc[mt][nt], 0, 0, 0);
    __syncthreads();
  }

  // epilogue: C/D layout col=l&15, row=(l>>4)*4+reg
  for (int nt = 0; nt < 4; ++nt) {
    int gc = bn * 128 + wn + nt * 16 + r;
    float bv = bias ? bias[gc] : 0.f;
    for (int mt = 0; mt < 4; ++mt) {
      int gm = bm * 128 + wm + mt * 16 + q * 4;
      for (int rr = 0; rr < 4; ++rr) {
        float v = acc[mt][nt][rr] + bv;
        if (act == 1) v = fmaxf(v, 0.f);
        else if (act == 2) v = (v >= 0.f) ? v : v * RRELU_SLOPE;
        C[(size_t)(gm + rr) * ldc + gc] = v;
      }
    }
  }
}

// ---------------------------------------------------------------------------
// Edge message + aggregate + update (v3).
// Round-2 finding: wave-uniform loads of (src,dst,ea) scalarize to s_load
// through the tiny scalar K$ (64KB ea/block vs ~16KB K$) -> serialized
// misses dominated (698us, VALUBusy 7%). Fix: batch-load 64 edges' metadata
// with per-lane (coalesced, VMEM-path) loads, then v_readlane-broadcast each
// edge's record. One vmcnt wait per 64 edges instead of scalar misses/edge.
// ---------------------------------------------------------------------------
__global__ __launch_bounds__(1024, 4) void edge_conv(
    const float* __restrict__ y,
    const int* __restrict__ eidx,           // [2, E]
    const unsigned int* __restrict__ ea_h2, // [E, 8] half2 pairs
    const unsigned int* __restrict__ We_h2, // [8, 256] half2 (k-pairs)
    float* __restrict__ x_out)
{
  __shared__ float agg[64 * 128];
  __shared__ float ystage[64 * 128];
  const int g = blockIdx.x >> 1;
  const int dbase = (blockIdx.x & 1) * 128;
  const int tid = threadIdx.x;
  // zero agg + stage y message-half for this graph: ystage[n][dd]
  for (int i = tid; i < 8192; i += 1024) {
    agg[i] = 0.f;
    int n = i >> 7, dd = i & 127;
    ystage[i] = y[(size_t)(g * 64 + n) * 512 + dbase + dd];
  }
  const int l = tid & 63;
  const int d0 = dbase + l, d1 = d0 + 64;
  unsigned int we0[8], we1[8];
#pragma unroll
  for (int j = 0; j < 8; ++j) {
    we0[j] = We_h2[j * 256 + d0];
    we1[j] = We_h2[j * 256 + d1];
  }
  __syncthreads();
  const int w = tid >> 6;
  const int ebase = g * 2048 + w * 128;

  for (int b = 0; b < 2; ++b) {
    // lane l <-> edge (ebase + b*64 + l): per-lane coalesced VMEM loads
    const int me = ebase + b * 64 + l;
    int srcv = eidx[me];
    int dstv = eidx[E_TOTAL + me];
    uint4 eaA = *(const uint4*)(ea_h2 + (size_t)me * 8);
    uint4 eaB = *(const uint4*)(ea_h2 + (size_t)me * 8 + 4);

    for (int e = 0; e < 64; ++e) {
      // broadcast edge e's record from lane e (VALU, no memory)
      const int src = __builtin_amdgcn_readlane(srcv, e);
      const int dst = __builtin_amdgcn_readlane(dstv, e);
      const unsigned a0 = (unsigned)__builtin_amdgcn_readlane((int)eaA.x, e);
      const unsigned a1 = (unsigned)__builtin_amdgcn_readlane((int)eaA.y, e);
      const unsigned a2 = (unsigned)__builtin_amdgcn_readlane((int)eaA.z, e);
      const unsigned a3 = (unsigned)__builtin_amdgcn_readlane((int)eaA.w, e);
      const unsigned a4 = (unsigned)__builtin_amdgcn_readlane((int)eaB.x, e);
      const unsigned a5 = (unsigned)__builtin_amdgcn_readlane((int)eaB.y, e);
      const unsigned a6 = (unsigned)__builtin_amdgcn_readlane((int)eaB.z, e);
      const unsigned a7 = (unsigned)__builtin_amdgcn_readlane((int)eaB.w, e);

      const int sl = src & 63;
      float m0 = ystage[sl * 128 + l];
      float m1 = ystage[sl * 128 + l + 64];
      m0 = dot2f(a0, we0[0], m0); m1 = dot2f(a0, we1[0], m1);
      m0 = dot2f(a1, we0[1], m0); m1 = dot2f(a1, we1[1], m1);
      m0 = dot2f(a2, we0[2], m0); m1 = dot2f(a2, we1[2], m1);
      m0 = dot2f(a3, we0[3], m0); m1 = dot2f(a3, we1[3], m1);
      m0 = dot2f(a4, we0[4], m0); m1 = dot2f(a4, we1[4], m1);
      m0 = dot2f(a5, we0[5], m0); m1 = dot2f(a5, we1[5], m1);
      m0 = dot2f(a6, we0[6], m0); m1 = dot2f(a6, we1[6], m1);
      m0 = dot2f(a7, we0[7], m0); m1 = dot2f(a7, we1[7], m1);
      const int dl = (dst & 63) * 128 + l;
      atomicAdd(&agg[dl], fmaxf(m0, 0.f));
      atomicAdd(&agg[dl + 64], fmaxf(m1, 0.f));
    }
  }
  __syncthreads();
  for (int i = tid; i < 8192; i += 1024) {
    int n = i >> 7, dd = i & 127;
    float v = y[(size_t)(g * 64 + n) * 512 + 256 + dbase + dd] + agg[i];
    x_out[(size_t)(g * 64 + n) * 256 + dbase + dd] = fmaxf(v, 0.f);
  }
}

// ---------------------------------------------------------------------------
// dot_pool: per graph, item = X1 @ X2^T [64x64]; write max & mean to fusion.
// ---------------------------------------------------------------------------
__global__ __launch_bounds__(256) void dot_pool_k(
    const float* __restrict__ x1, const float* __restrict__ x2,
    float* __restrict__ fusion, int step)
{
  __shared__ float s1[64][68];
  __shared__ float s2[64][68];
  __shared__ float redm[4], reds[4];
  const int g = blockIdx.x;
  const int tid = threadIdx.x;
  const int ti = (tid & 15) * 4;
  const int tj = (tid >> 4) * 4;
  float acc[4][4] = {};
  for (int kc = 0; kc < 256; kc += 64) {
    for (int rr = 0; rr < 4; ++rr) {
      int lin = tid + rr * 256;
      int n = lin >> 4, k4 = (lin & 15) * 4;
      *(float4*)&s1[n][k4] = *(const float4*)(x1 + (size_t)(g * 64 + n) * 256 + kc + k4);
      *(float4*)&s2[n][k4] = *(const float4*)(x2 + (size_t)(g * 64 + n) * 256 + kc + k4);
    }
    __syncthreads();
    for (int kk = 0; kk < 64; kk += 4) {
      float4 a0 = *(const float4*)&s1[ti + 0][kk];
      float4 a1 = *(const float4*)&s1[ti + 1][kk];
      float4 a2 = *(const float4*)&s1[ti + 2][kk];
      float4 a3 = *(const float4*)&s1[ti + 3][kk];
      float4 b0 = *(const float4*)&s2[tj + 0][kk];
      float4 b1 = *(const float4*)&s2[tj + 1][kk];
      float4 b2 = *(const float4*)&s2[tj + 2][kk];
      float4 b3 = *(const float4*)&s2[tj + 3][kk];
      acc[0][0] += dot4(a0, b0); acc[0][1] += dot4(a0, b1);
      acc[0][2] += dot4(a0, b2); acc[0][3] += dot4(a0, b3);
      acc[1][0] += dot4(a1, b0); acc[1][1] += dot4(a1, b1);
      acc[1][2] += dot4(a1, b2); acc[1][3] += dot4(a1, b3);
      acc[2][0] += dot4(a2, b0); acc[2][1] += dot4(a2, b1);
      acc[2][2] += dot4(a2, b2); acc[2][3] += dot4(a2, b3);
      acc[3][0] += dot4(a3, b0); acc[3][1] += dot4(a3, b1);
      acc[3][2] += dot4(a3, b2); acc[3][3] += dot4(a3, b3);
    }
    __syncthreads();
  }
  float mymax = -1e30f, mysum = 0.f;
  for (int i = 0; i < 4; ++i)
    for (int j = 0; j < 4; ++j) {
      mymax = fmaxf(mymax, acc[i][j]);
      mysum += acc[i][j];
    }
  for (int off = 32; off; off >>= 1) {
    mymax = fmaxf(mymax, __shfl_down(mymax, off, 64));
    mysum += __shfl_down(mysum, off, 64);
  }
  if ((tid & 63) == 0) { redm[tid >> 6] = mymax; reds[tid >> 6] = mysum; }
  __syncthreads();
  if (tid == 0) {
    float gm = fmaxf(fmaxf(redm[0], redm[1]), fmaxf(redm[2], redm[3]));
    float gs = reds[0] + reds[1] + reds[2] + reds[3];
    fusion[g * 6 + step * 2] = gm;
    fusion[g * 6 + step * 2 + 1] = gs * (1.f / 4096.f);
  }
}

// ---------------------------------------------------------------------------
// readout: R[g] = [mean(256) | sum(256) | top3-by-last-col rows (3x256)]
// Stable tie-break: strict '>' picks lowest index first (matches stable argsort)
// ---------------------------------------------------------------------------
__global__ __launch_bounds__(256) void readout_assemble(
    const float* __restrict__ xm, float* __restrict__ R)
{
  __shared__ float lastcol[64];
  __shared__ int topi[3];
  const int g = blockIdx.x, d = threadIdx.x;
  float s = 0.f;
  for (int n = 0; n < 64; ++n) s += xm[(size_t)(g * 64 + n) * 256 + d];
  R[(size_t)g * 1280 + d] = s * (1.f / 64.f);
  R[(size_t)g * 1280 + 256 + d] = s;
  if (d < 64) lastcol[d] = xm[(size_t)(g * 64 + d) * 256 + 255];
  __syncthreads();
  if (d == 0) {
    unsigned long long used = 0;
    for (int j = 0; j < 3; ++j) {
      float best = -1e30f;
      int bi = 0;
      for (int n = 0; n < 64; ++n) {
        if ((used >> n) & 1ull) continue;
        if (lastcol[n] > best) { best = lastcol[n]; bi = n; }
      }
      used |= (1ull << bi);
      topi[j] = bi;
    }
  }
  __syncthreads();
  for (int j = 0; j < 3; ++j)
    R[(size_t)g * 1280 + 512 + j * 256 + d] =
        xm[(size_t)(g * 64 + topi[j]) * 256 + d];
}

// ---------------------------------------------------------------------------
// final head: out = (cat(outm1, outm2, fusion) @ Wo1 + bo1) @ Wo2 + bo2
// ---------------------------------------------------------------------------
__global__ __launch_bounds__(256) void final_head(
    const float* __restrict__ outm1, const float* __restrict__ outm2,
    const float* __restrict__ fusion,
    const float* __restrict__ Wo1, const float* __restrict__ bo1,
    const float* __restrict__ Wo2, const float* __restrict__ bo2,
    float* __restrict__ out)
{
  __shared__ float cat[520];
  __shared__ float r0s[4], r1s[4];
  const int g = blockIdx.x, t = threadIdx.x;
  cat[t] = outm1[(size_t)g * 256 + t];
  cat[256 + t] = outm2[(size_t)g * 256 + t];
  if (t < 6) cat[512 + t] = fusion[g * 6 + t];
  __syncthreads();
  float acc = bo1[t];
  for (int k = 0; k < 518; ++k) acc = fmaf(cat[k], Wo1[(size_t)k * 256 + t], acc);
  float p0 = acc * Wo2[t * 2];
  float p1 = acc * Wo2[t * 2 + 1];
  for (int off = 32; off; off >>= 1) {
    p0 += __shfl_down(p0, off, 64);
    p1 += __shfl_down(p1, off, 64);
  }
  if ((t & 63) == 0) { r0s[t >> 6] = p0; r1s[t >> 6] = p1; }
  __syncthreads();
  if (t == 0) {
    out[g * 2] = r0s[0] + r0s[1] + r0s[2] + r0s[3] + bo2[0];
    out[g * 2 + 1] = r1s[0] + r1s[1] + r1s[2] + r1s[3] + bo2[1];
  }
}

// ---------------------------------------------------------------------------
// Prep kernels (run every launch; ws is re-poisoned each call)
// ---------------------------------------------------------------------------
// src [K][256] fp32 -> dst [256][K] bf16. grid = K blocks x 256.
__global__ void transpose_cvt256(const float* __restrict__ src,
                                 unsigned short* __restrict__ dst, int K)
{
  int k = blockIdx.x, n = threadIdx.x;
  dst[n * K + k] = f2bf(src[k * 256 + n]);
}

__global__ void misc_prep(
    const float* bm1, const float* bs1, const float* bm2, const float* bs2,
    const float* We1, const float* We2,
    float* bcat1, float* bcat2,
    unsigned int* weh1, unsigned int* weh2)
{
  int idx = blockIdx.x * 256 + threadIdx.x;  // grid 20 -> 5120
  if (idx < 512) {
    bcat1[idx] = idx < 256 ? bm1[idx] : bs1[idx - 256];
  } else if (idx < 1024) {
    int i = idx - 512;
    bcat2[i] = i < 256 ? bm2[i] : bs2[i - 256];
  } else if (idx < 3072) {
    int i = idx - 1024, j = i >> 8, d = i & 255;
    weh1[i] = pack_h2(We1[(2 * j) * 256 + d], We1[(2 * j + 1) * 256 + d]);
  } else if (idx < 5120) {
    int i = idx - 3072, j = i >> 8, d = i & 255;
    weh2[i] = pack_h2(We2[(2 * j) * 256 + d], We2[(2 * j + 1) * 256 + d]);
  }
}

__global__ void ea_pack(const float* __restrict__ ea1,
                        const float* __restrict__ ea2,
                        unsigned int* __restrict__ d1,
                        unsigned int* __restrict__ d2)
{
  int idx = blockIdx.x * 256 + threadIdx.x;  // grid 32768 -> 2*E*8
  const int n = E_TOTAL * 8;
  const float* s;
  unsigned int* d;
  int r;
  if (idx < n) { s = ea1; d = d1; r = idx; }
  else { s = ea2; d = d2; r = idx - n; }
  int e = r >> 3, j = r & 7;
  float2 v = *(const float2*)(s + (size_t)e * 16 + 2 * j);
  d[r] = pack_h2(v.x, v.y);
}

// ---------------------------------------------------------------------------
extern "C" void kernel_launch(void* const* d_in, const int* in_sizes, int n_in,
                              void* d_out, int out_size, void* d_ws, size_t ws_size,
                              hipStream_t stream)
{
  const float* x1 = (const float*)d_in[0];
  const int* ei1 = (const int*)d_in[1];
  const float* ea1 = (const float*)d_in[2];
  const float* x2 = (const float*)d_in[4];
  const int* ei2 = (const int*)d_in[5];
  const float* ea2 = (const float*)d_in[6];
  const float* W0_1 = (const float*)d_in[8];
  const float* b0_1 = (const float*)d_in[9];
  const float* W0_2 = (const float*)d_in[10];
  const float* b0_2 = (const float*)d_in[11];
  const float* Wn1 = (const float*)d_in[12];
  const float* We1 = (const float*)d_in[13];
  const float* bm1 = (const float*)d_in[14];
  const float* Ws1 = (const float*)d_in[15];
  const float* bs1 = (const float*)d_in[16];
  const float* Wn2 = (const float*)d_in[17];
  const float* We2 = (const float*)d_in[18];
  const float* bm2 = (const float*)d_in[19];
  const float* Ws2 = (const float*)d_in[20];
  const float* bs2 = (const float*)d_in[21];
  const float* Wf1 = (const float*)d_in[22];
  const float* bf1 = (const float*)d_in[23];
  const float* Wf2 = (const float*)d_in[24];
  const float* bf2 = (const float*)d_in[25];
  const float* Wo1 = (const float*)d_in[26];
  const float* bo1 = (const float*)d_in[27];
  const float* Wo2 = (const float*)d_in[28];
  const float* bo2 = (const float*)d_in[29];
  float* out = (float*)d_out;

  float* w = (float*)d_ws;
  size_t off = 0;
  auto alloc = [&](size_t nf) { float* p = w + off; off += nf; return p; };
  float* xmA1 = alloc(4194304);
  float* xmA2 = alloc(4194304);
  float* xmB1 = alloc(4194304);
  float* xmB2 = alloc(4194304);
  float* y1 = alloc(8388608);
  float* y2 = alloc(8388608);
  float* R1 = alloc(327680);
  float* R2 = alloc(327680);
  float* outm1 = alloc(65536);
  float* outm2 = alloc(65536);
  float* fusion = alloc(1536);
  float* bcat1 = alloc(512);
  float* bcat2 = alloc(512);
  unsigned short* W0T1 = (unsigned short*)alloc(16384);
  unsigned short* W0T2 = (unsigned short*)alloc(16384);
  unsigned short* WcT1 = (unsigned short*)alloc(65536);
  unsigned short* WcT2 = (unsigned short*)alloc(65536);
  unsigned short* WfT1 = (unsigned short*)alloc(163840);
  unsigned short* WfT2 = (unsigned short*)alloc(163840);
  unsigned int* weh1 = (unsigned int*)alloc(2048);
  unsigned int* weh2 = (unsigned int*)alloc(2048);
  unsigned int* eah1 = (unsigned int*)alloc(4194304);
  unsigned int* eah2 = (unsigned int*)alloc(4194304);
  (void)in_sizes; (void)n_in; (void)out_size; (void)ws_size;

  // ---- prep ----
  transpose_cvt256<<<128, 256, 0, stream>>>(W0_1, W0T1, 128);
  transpose_cvt256<<<128, 256, 0, stream>>>(W0_2, W0T2, 128);
  transpose_cvt256<<<256, 256, 0, stream>>>(Wn1, WcT1, 256);
  transpose_cvt256<<<256, 256, 0, stream>>>(Ws1, WcT1 + 65536, 256);
  transpose_cvt256<<<256, 256, 0, stream>>>(Wn2, WcT2, 256);
  transpose_cvt256<<<256, 256, 0, stream>>>(Ws2, WcT2 + 65536, 256);
  transpose_cvt256<<<1280, 256, 0, stream>>>(Wf1, WfT1, 1280);
  transpose_cvt256<<<1280, 256, 0, stream>>>(Wf2, WfT2, 1280);
  misc_prep<<<20, 256, 0, stream>>>(bm1, bs1, bm2, bs2, We1, We2,
                                    bcat1, bcat2, weh1, weh2);
  ea_pack<<<32768, 256, 0, stream>>>(ea1, ea2, eah1, eah2);

  // ---- embed: xm = rrelu(x @ W0 + b0) ----
  gemm_bf16<<<dim3(128, 2), 256, 0, stream>>>(x1, 128, W0T1, b0_1, xmA1, 256, 128, 2);
  gemm_bf16<<<dim3(128, 2), 256, 0, stream>>>(x2, 128, W0T2, b0_2, xmA2, 256, 128, 2);

  // ---- 3 message-passing steps ----
  float* cur1 = xmA1; float* cur2 = xmA2;
  float* nxt1 = xmB1; float* nxt2 = xmB2;
  for (int step = 0; step < 3; ++step) {
    gemm_bf16<<<dim3(128, 4), 256, 0, stream>>>(cur1, 256, WcT1, bcat1, y1, 512, 256, 0);
    gemm_bf16<<<dim3(128, 4), 256, 0, stream>>>(cur2, 256, WcT2, bcat2, y2, 512, 256, 0);
    edge_conv<<<512, 1024, 0, stream>>>(y1, ei1, eah1, weh1, nxt1);
    edge_conv<<<512, 1024, 0, stream>>>(y2, ei2, eah2, weh2, nxt2);
    dot_pool_k<<<256, 256, 0, stream>>>(nxt1, nxt2, fusion, step);
    float* t1 = cur1; cur1 = nxt1; nxt1 = t1;
    float* t2 = cur2; cur2 = nxt2; nxt2 = t2;
  }

  // ---- readout + head ----
  readout_assemble<<<256, 256, 0, stream>>>(cur1, R1);
  readout_assemble<<<256, 256, 0, stream>>>(cur2, R2);
  gemm_bf16<<<dim3(2, 2), 256, 0, stream>>>(R1, 1280, WfT1, bf1, outm1, 256, 1280, 0);
  gemm_bf16<<<dim3(2, 2), 256, 0, stream>>>(R2, 1280, WfT2, bf2, outm2, 256, 1280, 0);
  final_head<<<256, 256, 0, stream>>>(outm1, outm2, fusion,
                                      Wo1, bo1, Wo2, bo2, out);
}

// Round 4
// 1196.541 us; speedup vs baseline: 3.8531x; 3.8453x over previous
//
#include <hip/hip_runtime.h>
#include <hip/hip_fp16.h>

// Problem constants (fixed by setup_inputs)
#define E_TOTAL 524288
#define RRELU_SLOPE 0.22916666666666666f

typedef float f32x4 __attribute__((ext_vector_type(4)));
typedef short short8_t __attribute__((ext_vector_type(8)));
typedef _Float16 h2_t __attribute__((ext_vector_type(2)));

#if defined(__has_builtin)
# if __has_builtin(__builtin_amdgcn_fdot2)
#  define HAVE_FDOT2 1
# endif
#endif

__device__ inline unsigned short f2bf(float x) {
  unsigned int u = __float_as_uint(x);
  u += 0x7FFFu + ((u >> 16) & 1u);   // RNE
  return (unsigned short)(u >> 16);
}

__device__ inline unsigned int pack_h2(float a, float b) {
  __half2 h = __floats2half2_rn(a, b);
  return __builtin_bit_cast(unsigned int, h);
}

__device__ inline float dot2f(unsigned int a, unsigned int b, float c) {
#ifdef HAVE_FDOT2
  return __builtin_amdgcn_fdot2(__builtin_bit_cast(h2_t, a),
                                __builtin_bit_cast(h2_t, b), c, false);
#else
  h2_t av = __builtin_bit_cast(h2_t, a);
  h2_t bv = __builtin_bit_cast(h2_t, b);
  return c + (float)av[0] * (float)bv[0] + (float)av[1] * (float)bv[1];
#endif
}

__device__ inline float dot4(float4 a, float4 b) {
  return a.x * b.x + a.y * b.y + a.z * b.z + a.w * b.w;
}

// ---------------------------------------------------------------------------
// Generic bf16-MFMA GEMM: C[M,N] = act(A[M,K](fp32) @ B[K,N] + bias)
// B passed pre-transposed+converted: BT[N][K] bf16. Grid: (M/128, N/128).
// act: 0=none, 1=relu, 2=rrelu
// ---------------------------------------------------------------------------
__global__ __launch_bounds__(256) void gemm_bf16(
    const float* __restrict__ A, int lda,
    const unsigned short* __restrict__ BT,
    const float* __restrict__ bias,
    float* __restrict__ C, int ldc,
    int K, int act)
{
  __shared__ unsigned short As[128][32];
  __shared__ unsigned short Bs[128][32];
  const int tid = threadIdx.x;
  const int bm = blockIdx.x, bn = blockIdx.y;
  const int w = tid >> 6, l = tid & 63;
  const int wm = (w & 1) * 64, wn = (w >> 1) * 64;
  const int q = l >> 4, r = l & 15;

  f32x4 acc[4][4];
  for (int i = 0; i < 4; ++i)
    for (int j = 0; j < 4; ++j)
      acc[i][j] = (f32x4){0.f, 0.f, 0.f, 0.f};

  const int sm = tid >> 1;        // 0..127 (row within tile)
  const int sk = (tid & 1) * 16;  // 0 or 16
  const float* ap = A + (size_t)(bm * 128 + sm) * lda + sk;
  const unsigned short* bp = BT + (size_t)(bn * 128 + sm) * K + sk;

  for (int k0 = 0; k0 < K; k0 += 32) {
    // stage A (fp32 -> bf16)
    float4 f0 = *(const float4*)(ap + k0);
    float4 f1 = *(const float4*)(ap + k0 + 4);
    float4 f2 = *(const float4*)(ap + k0 + 8);
    float4 f3 = *(const float4*)(ap + k0 + 12);
    uint4 p0, p1;
    p0.x = (unsigned)f2bf(f0.x) | ((unsigned)f2bf(f0.y) << 16);
    p0.y = (unsigned)f2bf(f0.z) | ((unsigned)f2bf(f0.w) << 16);
    p0.z = (unsigned)f2bf(f1.x) | ((unsigned)f2bf(f1.y) << 16);
    p0.w = (unsigned)f2bf(f1.z) | ((unsigned)f2bf(f1.w) << 16);
    p1.x = (unsigned)f2bf(f2.x) | ((unsigned)f2bf(f2.y) << 16);
    p1.y = (unsigned)f2bf(f2.z) | ((unsigned)f2bf(f2.w) << 16);
    p1.z = (unsigned)f2bf(f3.x) | ((unsigned)f2bf(f3.y) << 16);
    p1.w = (unsigned)f2bf(f3.z) | ((unsigned)f2bf(f3.w) << 16);
    *(uint4*)&As[sm][sk] = p0;
    *(uint4*)&As[sm][sk + 8] = p1;
    // stage B (already bf16, [n][k] layout)
    uint4 b0 = *(const uint4*)(bp + k0);
    uint4 b1 = *(const uint4*)(bp + k0 + 8);
    *(uint4*)&Bs[sm][sk] = b0;
    *(uint4*)&Bs[sm][sk + 8] = b1;
    __syncthreads();

    short8_t af[4], bfr[4];
    for (int mt = 0; mt < 4; ++mt)
      af[mt] = *(const short8_t*)&As[wm + mt * 16 + r][q * 8];
    for (int nt = 0; nt < 4; ++nt)
      bfr[nt] = *(const short8_t*)&Bs[wn + nt * 16 + r][q * 8];
    for (int mt = 0; mt < 4; ++mt)
      for (int nt = 0; nt < 4; ++nt)
        acc[mt][nt] = __builtin_amdgcn_mfma_f32_16x16x32_bf16(
            af[mt], bfr[nt], acc[mt][nt], 0, 0, 0);
    __syncthreads();
  }

  // epilogue: C/D layout col=l&15, row=(l>>4)*4+reg
  for (int nt = 0; nt < 4; ++nt) {
    int gc = bn * 128 + wn + nt * 16 + r;
    float bv = bias ? bias[gc] : 0.f;
    for (int mt = 0; mt < 4; ++mt) {
      int gm = bm * 128 + wm + mt * 16 + q * 4;
      for (int rr = 0; rr < 4; ++rr) {
        float v = acc[mt][nt][rr] + bv;
        if (act == 1) v = fmaxf(v, 0.f);
        else if (act == 2) v = (v >= 0.f) ? v : v * RRELU_SLOPE;
        C[(size_t)(gm + rr) * ldc + gc] = v;
      }
    }
  }
}

// ---------------------------------------------------------------------------
// Per-graph counting sort of edges by destination node.
// One block per graph (2048 edges, 64 dst buckets).
// Outputs: meta[p] = src|dst<<8 (sorted), perm[p] = original local edge idx,
//          starts[g*65+n] = bucket start offsets (local, 0..2048).
// ---------------------------------------------------------------------------
__global__ __launch_bounds__(256) void sort_edges(
    const int* __restrict__ eidx,
    int* __restrict__ meta, int* __restrict__ perm, int* __restrict__ starts)
{
  __shared__ int cnt[4][64];
  __shared__ int startS[65];
  __shared__ int cur[64];
  const int g = blockIdx.x, t = threadIdx.x, w = t >> 6;
  if (t < 256) cnt[t >> 6][t & 63] = 0;
  if (t < 64) cur[t] = 0;
  __syncthreads();
  for (int i = t; i < 2048; i += 256)
    atomicAdd(&cnt[w][eidx[E_TOTAL + g * 2048 + i] & 63], 1);
  __syncthreads();
  if (t == 0) {
    int acc = 0;
    for (int n = 0; n < 64; ++n) {
      startS[n] = acc;
      acc += cnt[0][n] + cnt[1][n] + cnt[2][n] + cnt[3][n];
    }
    startS[64] = acc;  // == 2048
  }
  __syncthreads();
  if (t < 65) starts[g * 65 + t] = startS[t];
  for (int i = t; i < 2048; i += 256) {
    int s = eidx[g * 2048 + i] & 63;
    int d = eidx[E_TOTAL + g * 2048 + i] & 63;
    int p = startS[d] + atomicAdd(&cur[d], 1);
    meta[g * 2048 + p] = s | (d << 8);
    perm[g * 2048 + p] = i;
  }
}

// ---------------------------------------------------------------------------
// Gather ea (fp32[16]) through the sort permutation, convert to 8 packed
// half2, store contiguously in sorted edge order. One lane per sorted edge.
// ---------------------------------------------------------------------------
__global__ __launch_bounds__(256) void ea_gather_pack(
    const float* __restrict__ ea, const int* __restrict__ perm,
    unsigned int* __restrict__ out)
{
  int p = blockIdx.x * 256 + threadIdx.x;  // 0..E-1
  int g = p >> 11;
  int i = perm[p];
  const float* s = ea + (size_t)(g * 2048 + i) * 16;
  float4 v0 = *(const float4*)(s);
  float4 v1 = *(const float4*)(s + 4);
  float4 v2 = *(const float4*)(s + 8);
  float4 v3 = *(const float4*)(s + 12);
  uint4 o0, o1;
  o0.x = pack_h2(v0.x, v0.y); o0.y = pack_h2(v0.z, v0.w);
  o0.z = pack_h2(v1.x, v1.y); o0.w = pack_h2(v1.z, v1.w);
  o1.x = pack_h2(v2.x, v2.y); o1.y = pack_h2(v2.z, v2.w);
  o1.z = pack_h2(v3.x, v3.y); o1.w = pack_h2(v3.z, v3.w);
  *(uint4*)(out + (size_t)p * 8) = o0;
  *(uint4*)(out + (size_t)p * 8 + 4) = o1;
}

// ---------------------------------------------------------------------------
// Edge message + aggregate + update (v4 — NO LDS atomics, no scalar loads).
// Rounds 1-3 all plateaued at ~690us with idle pipes; the invariant was the
// 2x per-edge shared-float atomicAdd (~200cyc/wave-op serialized per CU).
// Now: edges sorted by dst; wave w exclusively owns nodes [8w,8w+8) = one
// contiguous sorted run. Register accumulate (dst non-decreasing), flush to
// LDS agg with plain ds_writes on dst change. Metadata batch-loaded per-lane
// (VMEM, coalesced) + readlane broadcast (keeps round-2 fix).
// 512 thr/block, LDS 64KB -> 2 blocks/CU; launch_bounds(512,4) -> 128 VGPR.
// ---------------------------------------------------------------------------
__global__ __launch_bounds__(512, 4) void edge_conv(
    const float* __restrict__ y,
    const int* __restrict__ meta,           // [E] sorted: src|dst<<8
    const unsigned int* __restrict__ ea_h2, // [E, 8] half2 pairs (sorted)
    const unsigned int* __restrict__ We_h2, // [8, 256] half2 (k-pairs)
    const int* __restrict__ starts,         // [B*65]
    float* __restrict__ x_out)
{
  __shared__ float agg[8192];
  __shared__ float ystage[8192];
  const int g = blockIdx.x >> 1;
  const int dbase = (blockIdx.x & 1) * 128;
  const int tid = threadIdx.x;
  for (int i = tid; i < 8192; i += 512) {
    agg[i] = 0.f;
    int n = i >> 7, dd = i & 127;
    ystage[i] = y[(size_t)(g * 64 + n) * 512 + dbase + dd];
  }
  const int l = tid & 63;
  const int d0 = dbase + l, d1 = d0 + 64;
  unsigned int we0[8], we1[8];
#pragma unroll
  for (int j = 0; j < 8; ++j) {
    we0[j] = We_h2[j * 256 + d0];
    we1[j] = We_h2[j * 256 + d1];
  }
  __syncthreads();

  const int w = tid >> 6;  // wave 0..7 owns nodes [8w, 8w+8)
  const int estart = starts[g * 65 + w * 8];
  const int eend   = starts[g * 65 + w * 8 + 8];
  float c0 = 0.f, c1 = 0.f;
  int curnd = -1;

  for (int base = estart; base < eend; base += 64) {
    int lim = eend - base;
    if (lim > 64) lim = 64;
    const int idx = base + (l < lim ? l : lim - 1);
    const size_t gi = (size_t)g * 2048 + idx;
    int mv = meta[gi];
    uint4 eA = *(const uint4*)(ea_h2 + gi * 8);
    uint4 eB = *(const uint4*)(ea_h2 + gi * 8 + 4);

    for (int j = 0; j < lim; ++j) {
      const int m = __builtin_amdgcn_readlane(mv, j);
      const unsigned a0 = (unsigned)__builtin_amdgcn_readlane((int)eA.x, j);
      const unsigned a1 = (unsigned)__builtin_amdgcn_readlane((int)eA.y, j);
      const unsigned a2 = (unsigned)__builtin_amdgcn_readlane((int)eA.z, j);
      const unsigned a3 = (unsigned)__builtin_amdgcn_readlane((int)eA.w, j);
      const unsigned a4 = (unsigned)__builtin_amdgcn_readlane((int)eB.x, j);
      const unsigned a5 = (unsigned)__builtin_amdgcn_readlane((int)eB.y, j);
      const unsigned a6 = (unsigned)__builtin_amdgcn_readlane((int)eB.z, j);
      const unsigned a7 = (unsigned)__builtin_amdgcn_readlane((int)eB.w, j);
      const int src = m & 63;
      const int nd = (m >> 8) & 63;
      if (nd != curnd) {  // wave-uniform (m comes from readlane)
        if (curnd >= 0) {
          agg[curnd * 128 + l] = c0;
          agg[curnd * 128 + l + 64] = c1;
        }
        curnd = nd;
        c0 = 0.f;
        c1 = 0.f;
      }
      float m0 = ystage[src * 128 + l];
      float m1 = ystage[src * 128 + l + 64];
      m0 = dot2f(a0, we0[0], m0); m1 = dot2f(a0, we1[0], m1);
      m0 = dot2f(a1, we0[1], m0); m1 = dot2f(a1, we1[1], m1);
      m0 = dot2f(a2, we0[2], m0); m1 = dot2f(a2, we1[2], m1);
      m0 = dot2f(a3, we0[3], m0); m1 = dot2f(a3, we1[3], m1);
      m0 = dot2f(a4, we0[4], m0); m1 = dot2f(a4, we1[4], m1);
      m0 = dot2f(a5, we0[5], m0); m1 = dot2f(a5, we1[5], m1);
      m0 = dot2f(a6, we0[6], m0); m1 = dot2f(a6, we1[6], m1);
      m0 = dot2f(a7, we0[7], m0); m1 = dot2f(a7, we1[7], m1);
      c0 += fmaxf(m0, 0.f);
      c1 += fmaxf(m1, 0.f);
    }
  }
  if (curnd >= 0) {
    agg[curnd * 128 + l] = c0;
    agg[curnd * 128 + l + 64] = c1;
  }
  __syncthreads();
  for (int i = tid; i < 8192; i += 512) {
    int n = i >> 7, dd = i & 127;
    float v = y[(size_t)(g * 64 + n) * 512 + 256 + dbase + dd] + agg[i];
    x_out[(size_t)(g * 64 + n) * 256 + dbase + dd] = fmaxf(v, 0.f);
  }
}

// ---------------------------------------------------------------------------
// dot_pool: per graph, item = X1 @ X2^T [64x64]; write max & mean to fusion.
// ---------------------------------------------------------------------------
__global__ __launch_bounds__(256) void dot_pool_k(
    const float* __restrict__ x1, const float* __restrict__ x2,
    float* __restrict__ fusion, int step)
{
  __shared__ float s1[64][68];
  __shared__ float s2[64][68];
  __shared__ float redm[4], reds[4];
  const int g = blockIdx.x;
  const int tid = threadIdx.x;
  const int ti = (tid & 15) * 4;
  const int tj = (tid >> 4) * 4;
  float acc[4][4] = {};
  for (int kc = 0; kc < 256; kc += 64) {
    for (int rr = 0; rr < 4; ++rr) {
      int lin = tid + rr * 256;
      int n = lin >> 4, k4 = (lin & 15) * 4;
      *(float4*)&s1[n][k4] = *(const float4*)(x1 + (size_t)(g * 64 + n) * 256 + kc + k4);
      *(float4*)&s2[n][k4] = *(const float4*)(x2 + (size_t)(g * 64 + n) * 256 + kc + k4);
    }
    __syncthreads();
    for (int kk = 0; kk < 64; kk += 4) {
      float4 a0 = *(const float4*)&s1[ti + 0][kk];
      float4 a1 = *(const float4*)&s1[ti + 1][kk];
      float4 a2 = *(const float4*)&s1[ti + 2][kk];
      float4 a3 = *(const float4*)&s1[ti + 3][kk];
      float4 b0 = *(const float4*)&s2[tj + 0][kk];
      float4 b1 = *(const float4*)&s2[tj + 1][kk];
      float4 b2 = *(const float4*)&s2[tj + 2][kk];
      float4 b3 = *(const float4*)&s2[tj + 3][kk];
      acc[0][0] += dot4(a0, b0); acc[0][1] += dot4(a0, b1);
      acc[0][2] += dot4(a0, b2); acc[0][3] += dot4(a0, b3);
      acc[1][0] += dot4(a1, b0); acc[1][1] += dot4(a1, b1);
      acc[1][2] += dot4(a1, b2); acc[1][3] += dot4(a1, b3);
      acc[2][0] += dot4(a2, b0); acc[2][1] += dot4(a2, b1);
      acc[2][2] += dot4(a2, b2); acc[2][3] += dot4(a2, b3);
      acc[3][0] += dot4(a3, b0); acc[3][1] += dot4(a3, b1);
      acc[3][2] += dot4(a3, b2); acc[3][3] += dot4(a3, b3);
    }
    __syncthreads();
  }
  float mymax = -1e30f, mysum = 0.f;
  for (int i = 0; i < 4; ++i)
    for (int j = 0; j < 4; ++j) {
      mymax = fmaxf(mymax, acc[i][j]);
      mysum += acc[i][j];
    }
  for (int off = 32; off; off >>= 1) {
    mymax = fmaxf(mymax, __shfl_down(mymax, off, 64));
    mysum += __shfl_down(mysum, off, 64);
  }
  if ((tid & 63) == 0) { redm[tid >> 6] = mymax; reds[tid >> 6] = mysum; }
  __syncthreads();
  if (tid == 0) {
    float gm = fmaxf(fmaxf(redm[0], redm[1]), fmaxf(redm[2], redm[3]));
    float gs = reds[0] + reds[1] + reds[2] + reds[3];
    fusion[g * 6 + step * 2] = gm;
    fusion[g * 6 + step * 2 + 1] = gs * (1.f / 4096.f);
  }
}

// ---------------------------------------------------------------------------
// readout: R[g] = [mean(256) | sum(256) | top3-by-last-col rows (3x256)]
// Stable tie-break: strict '>' picks lowest index first (matches stable argsort)
// ---------------------------------------------------------------------------
__global__ __launch_bounds__(256) void readout_assemble(
    const float* __restrict__ xm, float* __restrict__ R)
{
  __shared__ float lastcol[64];
  __shared__ int topi[3];
  const int g = blockIdx.x, d = threadIdx.x;
  float s = 0.f;
  for (int n = 0; n < 64; ++n) s += xm[(size_t)(g * 64 + n) * 256 + d];
  R[(size_t)g * 1280 + d] = s * (1.f / 64.f);
  R[(size_t)g * 1280 + 256 + d] = s;
  if (d < 64) lastcol[d] = xm[(size_t)(g * 64 + d) * 256 + 255];
  __syncthreads();
  if (d == 0) {
    unsigned long long used = 0;
    for (int j = 0; j < 3; ++j) {
      float best = -1e30f;
      int bi = 0;
      for (int n = 0; n < 64; ++n) {
        if ((used >> n) & 1ull) continue;
        if (lastcol[n] > best) { best = lastcol[n]; bi = n; }
      }
      used |= (1ull << bi);
      topi[j] = bi;
    }
  }
  __syncthreads();
  for (int j = 0; j < 3; ++j)
    R[(size_t)g * 1280 + 512 + j * 256 + d] =
        xm[(size_t)(g * 64 + topi[j]) * 256 + d];
}

// ---------------------------------------------------------------------------
// final head: out = (cat(outm1, outm2, fusion) @ Wo1 + bo1) @ Wo2 + bo2
// ---------------------------------------------------------------------------
__global__ __launch_bounds__(256) void final_head(
    const float* __restrict__ outm1, const float* __restrict__ outm2,
    const float* __restrict__ fusion,
    const float* __restrict__ Wo1, const float* __restrict__ bo1,
    const float* __restrict__ Wo2, const float* __restrict__ bo2,
    float* __restrict__ out)
{
  __shared__ float cat[520];
  __shared__ float r0s[4], r1s[4];
  const int g = blockIdx.x, t = threadIdx.x;
  cat[t] = outm1[(size_t)g * 256 + t];
  cat[256 + t] = outm2[(size_t)g * 256 + t];
  if (t < 6) cat[512 + t] = fusion[g * 6 + t];
  __syncthreads();
  float acc = bo1[t];
  for (int k = 0; k < 518; ++k) acc = fmaf(cat[k], Wo1[(size_t)k * 256 + t], acc);
  float p0 = acc * Wo2[t * 2];
  float p1 = acc * Wo2[t * 2 + 1];
  for (int off = 32; off; off >>= 1) {
    p0 += __shfl_down(p0, off, 64);
    p1 += __shfl_down(p1, off, 64);
  }
  if ((t & 63) == 0) { r0s[t >> 6] = p0; r1s[t >> 6] = p1; }
  __syncthreads();
  if (t == 0) {
    out[g * 2] = r0s[0] + r0s[1] + r0s[2] + r0s[3] + bo2[0];
    out[g * 2 + 1] = r1s[0] + r1s[1] + r1s[2] + r1s[3] + bo2[1];
  }
}

// ---------------------------------------------------------------------------
// Prep kernels (run every launch; ws is re-poisoned each call)
// ---------------------------------------------------------------------------
// src [K][256] fp32 -> dst [256][K] bf16. grid = K blocks x 256.
__global__ void transpose_cvt256(const float* __restrict__ src,
                                 unsigned short* __restrict__ dst, int K)
{
  int k = blockIdx.x, n = threadIdx.x;
  dst[n * K + k] = f2bf(src[k * 256 + n]);
}

__global__ void misc_prep(
    const float* bm1, const float* bs1, const float* bm2, const float* bs2,
    const float* We1, const float* We2,
    float* bcat1, float* bcat2,
    unsigned int* weh1, unsigned int* weh2)
{
  int idx = blockIdx.x * 256 + threadIdx.x;  // grid 20 -> 5120
  if (idx < 512) {
    bcat1[idx] = idx < 256 ? bm1[idx] : bs1[idx - 256];
  } else if (idx < 1024) {
    int i = idx - 512;
    bcat2[i] = i < 256 ? bm2[i] : bs2[i - 256];
  } else if (idx < 3072) {
    int i = idx - 1024, j = i >> 8, d = i & 255;
    weh1[i] = pack_h2(We1[(2 * j) * 256 + d], We1[(2 * j + 1) * 256 + d]);
  } else if (idx < 5120) {
    int i = idx - 3072, j = i >> 8, d = i & 255;
    weh2[i] = pack_h2(We2[(2 * j) * 256 + d], We2[(2 * j + 1) * 256 + d]);
  }
}

// ---------------------------------------------------------------------------
extern "C" void kernel_launch(void* const* d_in, const int* in_sizes, int n_in,
                              void* d_out, int out_size, void* d_ws, size_t ws_size,
                              hipStream_t stream)
{
  const float* x1 = (const float*)d_in[0];
  const int* ei1 = (const int*)d_in[1];
  const float* ea1 = (const float*)d_in[2];
  const float* x2 = (const float*)d_in[4];
  const int* ei2 = (const int*)d_in[5];
  const float* ea2 = (const float*)d_in[6];
  const float* W0_1 = (const float*)d_in[8];
  const float* b0_1 = (const float*)d_in[9];
  const float* W0_2 = (const float*)d_in[10];
  const float* b0_2 = (const float*)d_in[11];
  const float* Wn1 = (const float*)d_in[12];
  const float* We1 = (const float*)d_in[13];
  const float* bm1 = (const float*)d_in[14];
  const float* Ws1 = (const float*)d_in[15];
  const float* bs1 = (const float*)d_in[16];
  const float* Wn2 = (const float*)d_in[17];
  const float* We2 = (const float*)d_in[18];
  const float* bm2 = (const float*)d_in[19];
  const float* Ws2 = (const float*)d_in[20];
  const float* bs2 = (const float*)d_in[21];
  const float* Wf1 = (const float*)d_in[22];
  const float* bf1 = (const float*)d_in[23];
  const float* Wf2 = (const float*)d_in[24];
  const float* bf2 = (const float*)d_in[25];
  const float* Wo1 = (const float*)d_in[26];
  const float* bo1 = (const float*)d_in[27];
  const float* Wo2 = (const float*)d_in[28];
  const float* bo2 = (const float*)d_in[29];
  float* out = (float*)d_out;

  float* w = (float*)d_ws;
  size_t off = 0;
  auto alloc = [&](size_t nf) { float* p = w + off; off += nf; return p; };
  float* xmA1 = alloc(4194304);
  float* xmA2 = alloc(4194304);
  float* xmB1 = alloc(4194304);
  float* xmB2 = alloc(4194304);
  float* y1 = alloc(8388608);
  float* y2 = alloc(8388608);
  float* R1 = alloc(327680);
  float* R2 = alloc(327680);
  float* outm1 = alloc(65536);
  float* outm2 = alloc(65536);
  float* fusion = alloc(1536);
  float* bcat1 = alloc(512);
  float* bcat2 = alloc(512);
  unsigned short* W0T1 = (unsigned short*)alloc(16384);
  unsigned short* W0T2 = (unsigned short*)alloc(16384);
  unsigned short* WcT1 = (unsigned short*)alloc(65536);
  unsigned short* WcT2 = (unsigned short*)alloc(65536);
  unsigned short* WfT1 = (unsigned short*)alloc(163840);
  unsigned short* WfT2 = (unsigned short*)alloc(163840);
  unsigned int* weh1 = (unsigned int*)alloc(2048);
  unsigned int* weh2 = (unsigned int*)alloc(2048);
  unsigned int* eah1 = (unsigned int*)alloc(4194304);
  unsigned int* eah2 = (unsigned int*)alloc(4194304);
  int* meta1 = (int*)alloc(524288);
  int* meta2 = (int*)alloc(524288);
  int* perm1 = (int*)alloc(524288);
  int* perm2 = (int*)alloc(524288);
  int* starts1 = (int*)alloc(16640);
  int* starts2 = (int*)alloc(16640);
  (void)in_sizes; (void)n_in; (void)out_size; (void)ws_size;

  // ---- prep ----
  sort_edges<<<256, 256, 0, stream>>>(ei1, meta1, perm1, starts1);
  sort_edges<<<256, 256, 0, stream>>>(ei2, meta2, perm2, starts2);
  ea_gather_pack<<<2048, 256, 0, stream>>>(ea1, perm1, eah1);
  ea_gather_pack<<<2048, 256, 0, stream>>>(ea2, perm2, eah2);
  transpose_cvt256<<<128, 256, 0, stream>>>(W0_1, W0T1, 128);
  transpose_cvt256<<<128, 256, 0, stream>>>(W0_2, W0T2, 128);
  transpose_cvt256<<<256, 256, 0, stream>>>(Wn1, WcT1, 256);
  transpose_cvt256<<<256, 256, 0, stream>>>(Ws1, WcT1 + 65536, 256);
  transpose_cvt256<<<256, 256, 0, stream>>>(Wn2, WcT2, 256);
  transpose_cvt256<<<256, 256, 0, stream>>>(Ws2, WcT2 + 65536, 256);
  transpose_cvt256<<<1280, 256, 0, stream>>>(Wf1, WfT1, 1280);
  transpose_cvt256<<<1280, 256, 0, stream>>>(Wf2, WfT2, 1280);
  misc_prep<<<20, 256, 0, stream>>>(bm1, bs1, bm2, bs2, We1, We2,
                                    bcat1, bcat2, weh1, weh2);

  // ---- embed: xm = rrelu(x @ W0 + b0) ----
  gemm_bf16<<<dim3(128, 2), 256, 0, stream>>>(x1, 128, W0T1, b0_1, xmA1, 256, 128, 2);
  gemm_bf16<<<dim3(128, 2), 256, 0, stream>>>(x2, 128, W0T2, b0_2, xmA2, 256, 128, 2);

  // ---- 3 message-passing steps ----
  float* cur1 = xmA1; float* cur2 = xmA2;
  float* nxt1 = xmB1; float* nxt2 = xmB2;
  for (int step = 0; step < 3; ++step) {
    gemm_bf16<<<dim3(128, 4), 256, 0, stream>>>(cur1, 256, WcT1, bcat1, y1, 512, 256, 0);
    gemm_bf16<<<dim3(128, 4), 256, 0, stream>>>(cur2, 256, WcT2, bcat2, y2, 512, 256, 0);
    edge_conv<<<512, 512, 0, stream>>>(y1, meta1, eah1, weh1, starts1, nxt1);
    edge_conv<<<512, 512, 0, stream>>>(y2, meta2, eah2, weh2, starts2, nxt2);
    dot_pool_k<<<256, 256, 0, stream>>>(nxt1, nxt2, fusion, step);
    float* t1 = cur1; cur1 = nxt1; nxt1 = t1;
    float* t2 = cur2; cur2 = nxt2; nxt2 = t2;
  }

  // ---- readout + head ----
  readout_assemble<<<256, 256, 0, stream>>>(cur1, R1);
  readout_assemble<<<256, 256, 0, stream>>>(cur2, R2);
  gemm_bf16<<<dim3(2, 2), 256, 0, stream>>>(R1, 1280, WfT1, bf1, outm1, 256, 1280, 0);
  gemm_bf16<<<dim3(2, 2), 256, 0, stream>>>(R2, 1280, WfT2, bf2, outm2, 256, 1280, 0);
  final_head<<<256, 256, 0, stream>>>(outm1, outm2, fusion,
                                      Wo1, bo1, Wo2, bo2, out);
}

// Round 5
// 863.986 us; speedup vs baseline: 5.3362x; 1.3849x over previous
//
#include <hip/hip_runtime.h>
#include <hip/hip_fp16.h>

// Problem constants (fixed by setup_inputs)
#define E_TOTAL 524288
#define RRELU_SLOPE 0.22916666666666666f

typedef float f32x4 __attribute__((ext_vector_type(4)));
typedef short short8_t __attribute__((ext_vector_type(8)));
typedef _Float16 h2_t __attribute__((ext_vector_type(2)));

#if defined(__has_builtin)
# if __has_builtin(__builtin_amdgcn_fdot2)
#  define HAVE_FDOT2 1
# endif
#endif

__device__ inline unsigned short f2bf(float x) {
  unsigned int u = __float_as_uint(x);
  u += 0x7FFFu + ((u >> 16) & 1u);   // RNE
  return (unsigned short)(u >> 16);
}

__device__ inline unsigned int pack_h2(float a, float b) {
  __half2 h = __floats2half2_rn(a, b);
  return __builtin_bit_cast(unsigned int, h);
}

__device__ inline float dot2f(unsigned int a, unsigned int b, float c) {
#ifdef HAVE_FDOT2
  return __builtin_amdgcn_fdot2(__builtin_bit_cast(h2_t, a),
                                __builtin_bit_cast(h2_t, b), c, false);
#else
  h2_t av = __builtin_bit_cast(h2_t, a);
  h2_t bv = __builtin_bit_cast(h2_t, b);
  return c + (float)av[0] * (float)bv[0] + (float)av[1] * (float)bv[1];
#endif
}

__device__ inline float dot4(float4 a, float4 b) {
  return a.x * b.x + a.y * b.y + a.z * b.z + a.w * b.w;
}

// ---------------------------------------------------------------------------
// Generic bf16-MFMA GEMM, dual parameter set selected by blockIdx.z.
// C[M,N] = act(A[M,K](fp32) @ B[K,N] + bias); BT[N][K] bf16.
// Grid: (M/128, N/128, 2). act: 0=none, 2=rrelu
// ---------------------------------------------------------------------------
__global__ __launch_bounds__(256) void gemm_bf16_dual(
    const float* __restrict__ A1, const unsigned short* __restrict__ BT1,
    const float* __restrict__ bias1, float* __restrict__ C1,
    const float* __restrict__ A2, const unsigned short* __restrict__ BT2,
    const float* __restrict__ bias2, float* __restrict__ C2,
    int lda, int ldc, int K, int act)
{
  const float* A = blockIdx.z ? A2 : A1;
  const unsigned short* BT = blockIdx.z ? BT2 : BT1;
  const float* bias = blockIdx.z ? bias2 : bias1;
  float* C = blockIdx.z ? C2 : C1;

  __shared__ unsigned short As[128][32];
  __shared__ unsigned short Bs[128][32];
  const int tid = threadIdx.x;
  const int bm = blockIdx.x, bn = blockIdx.y;
  const int w = tid >> 6, l = tid & 63;
  const int wm = (w & 1) * 64, wn = (w >> 1) * 64;
  const int q = l >> 4, r = l & 15;

  f32x4 acc[4][4];
  for (int i = 0; i < 4; ++i)
    for (int j = 0; j < 4; ++j)
      acc[i][j] = (f32x4){0.f, 0.f, 0.f, 0.f};

  const int sm = tid >> 1;
  const int sk = (tid & 1) * 16;
  const float* ap = A + (size_t)(bm * 128 + sm) * lda + sk;
  const unsigned short* bp = BT + (size_t)(bn * 128 + sm) * K + sk;

  for (int k0 = 0; k0 < K; k0 += 32) {
    float4 f0 = *(const float4*)(ap + k0);
    float4 f1 = *(const float4*)(ap + k0 + 4);
    float4 f2 = *(const float4*)(ap + k0 + 8);
    float4 f3 = *(const float4*)(ap + k0 + 12);
    uint4 p0, p1;
    p0.x = (unsigned)f2bf(f0.x) | ((unsigned)f2bf(f0.y) << 16);
    p0.y = (unsigned)f2bf(f0.z) | ((unsigned)f2bf(f0.w) << 16);
    p0.z = (unsigned)f2bf(f1.x) | ((unsigned)f2bf(f1.y) << 16);
    p0.w = (unsigned)f2bf(f1.z) | ((unsigned)f2bf(f1.w) << 16);
    p1.x = (unsigned)f2bf(f2.x) | ((unsigned)f2bf(f2.y) << 16);
    p1.y = (unsigned)f2bf(f2.z) | ((unsigned)f2bf(f2.w) << 16);
    p1.z = (unsigned)f2bf(f3.x) | ((unsigned)f2bf(f3.y) << 16);
    p1.w = (unsigned)f2bf(f3.z) | ((unsigned)f2bf(f3.w) << 16);
    *(uint4*)&As[sm][sk] = p0;
    *(uint4*)&As[sm][sk + 8] = p1;
    uint4 b0 = *(const uint4*)(bp + k0);
    uint4 b1 = *(const uint4*)(bp + k0 + 8);
    *(uint4*)&Bs[sm][sk] = b0;
    *(uint4*)&Bs[sm][sk + 8] = b1;
    __syncthreads();

    short8_t af[4], bfr[4];
    for (int mt = 0; mt < 4; ++mt)
      af[mt] = *(const short8_t*)&As[wm + mt * 16 + r][q * 8];
    for (int nt = 0; nt < 4; ++nt)
      bfr[nt] = *(const short8_t*)&Bs[wn + nt * 16 + r][q * 8];
    for (int mt = 0; mt < 4; ++mt)
      for (int nt = 0; nt < 4; ++nt)
        acc[mt][nt] = __builtin_amdgcn_mfma_f32_16x16x32_bf16(
            af[mt], bfr[nt], acc[mt][nt], 0, 0, 0);
    __syncthreads();
  }

  for (int nt = 0; nt < 4; ++nt) {
    int gc = bn * 128 + wn + nt * 16 + r;
    float bv = bias ? bias[gc] : 0.f;
    for (int mt = 0; mt < 4; ++mt) {
      int gm = bm * 128 + wm + mt * 16 + q * 4;
      for (int rr = 0; rr < 4; ++rr) {
        float v = acc[mt][nt][rr] + bv;
        if (act == 2) v = (v >= 0.f) ? v : v * RRELU_SLOPE;
        C[(size_t)(gm + rr) * ldc + gc] = v;
      }
    }
  }
}

// ---------------------------------------------------------------------------
// Per-graph counting sort of edges by destination node (dual-mol grid 512).
// ---------------------------------------------------------------------------
__global__ __launch_bounds__(256) void sort_edges_dual(
    const int* __restrict__ ei1, const int* __restrict__ ei2,
    int* __restrict__ meta1, int* __restrict__ meta2,
    int* __restrict__ perm1, int* __restrict__ perm2,
    int* __restrict__ starts1, int* __restrict__ starts2)
{
  const int mol = blockIdx.x >> 8;
  const int g = blockIdx.x & 255;
  const int* eidx = mol ? ei2 : ei1;
  int* meta = mol ? meta2 : meta1;
  int* perm = mol ? perm2 : perm1;
  int* starts = mol ? starts2 : starts1;

  __shared__ int cnt[4][64];
  __shared__ int startS[65];
  __shared__ int cur[64];
  const int t = threadIdx.x, w = t >> 6;
  cnt[w][t & 63] = 0;
  if (t < 64) cur[t] = 0;
  __syncthreads();
  for (int i = t; i < 2048; i += 256)
    atomicAdd(&cnt[w][eidx[E_TOTAL + g * 2048 + i] & 63], 1);
  __syncthreads();
  if (t == 0) {
    int acc = 0;
    for (int n = 0; n < 64; ++n) {
      startS[n] = acc;
      acc += cnt[0][n] + cnt[1][n] + cnt[2][n] + cnt[3][n];
    }
    startS[64] = acc;
  }
  __syncthreads();
  if (t < 65) starts[g * 65 + t] = startS[t];
  for (int i = t; i < 2048; i += 256) {
    int s = eidx[g * 2048 + i] & 63;
    int d = eidx[E_TOTAL + g * 2048 + i] & 63;
    int p = startS[d] + atomicAdd(&cur[d], 1);
    meta[g * 2048 + p] = s | (d << 8);
    perm[g * 2048 + p] = i;
  }
}

// ---------------------------------------------------------------------------
// Gather ea through sort permutation, pack to 8 half2 dwords (dual, grid 4096)
// ---------------------------------------------------------------------------
__global__ __launch_bounds__(256) void ea_gather_pack_dual(
    const float* __restrict__ ea1, const float* __restrict__ ea2,
    const int* __restrict__ perm1, const int* __restrict__ perm2,
    unsigned int* __restrict__ o1, unsigned int* __restrict__ o2)
{
  const int mol = blockIdx.x >> 11;
  const float* ea = mol ? ea2 : ea1;
  const int* perm = mol ? perm2 : perm1;
  unsigned int* out = mol ? o2 : o1;
  int p = (blockIdx.x & 2047) * 256 + threadIdx.x;  // 0..E-1
  int g = p >> 11;
  int i = perm[p];
  const float* s = ea + (size_t)(g * 2048 + i) * 16;
  float4 v0 = *(const float4*)(s);
  float4 v1 = *(const float4*)(s + 4);
  float4 v2 = *(const float4*)(s + 8);
  float4 v3 = *(const float4*)(s + 12);
  uint4 q0, q1;
  q0.x = pack_h2(v0.x, v0.y); q0.y = pack_h2(v0.z, v0.w);
  q0.z = pack_h2(v1.x, v1.y); q0.w = pack_h2(v1.z, v1.w);
  q1.x = pack_h2(v2.x, v2.y); q1.y = pack_h2(v2.z, v2.w);
  q1.z = pack_h2(v3.x, v3.y); q1.w = pack_h2(v3.z, v3.w);
  *(uint4*)(out + (size_t)p * 8) = q0;
  *(uint4*)(out + (size_t)p * 8 + 4) = q1;
}

// ---------------------------------------------------------------------------
// Edge conv v5: dst-sorted, register-accumulate (round-4 win) PLUS:
//  - ea broadcast via wave-private LDS slice (2x ds_read_b128 same-addr
//    broadcast) instead of 8 v_readlane per edge (cross-lane VALU was ~60%
//    of the measured 82 cyc/edge)
//  - ystage packed bf16 pairs (d,d+64): 1 ds_read + 2 bit-ops, frees 16KB
//    so ea staging fits in the same 64KB/block (2 blocks/CU preserved)
//  - meta keeps 1 readlane (SGPR result -> scalar flush branch)
// Dual-mol via blockIdx.z. Grid (512,1,2).
// ---------------------------------------------------------------------------
__global__ __launch_bounds__(512, 4) void edge_conv_dual(
    const float* __restrict__ y1, const int* __restrict__ meta1,
    const unsigned int* __restrict__ eas1, const unsigned int* __restrict__ wep1,
    const int* __restrict__ st1, float* __restrict__ xo1,
    const float* __restrict__ y2, const int* __restrict__ meta2,
    const unsigned int* __restrict__ eas2, const unsigned int* __restrict__ wep2,
    const int* __restrict__ st2, float* __restrict__ xo2)
{
  const float* y; const int* meta; const unsigned int* eas;
  const unsigned int* wep; const int* st; float* xo;
  if (blockIdx.z == 0) { y = y1; meta = meta1; eas = eas1; wep = wep1; st = st1; xo = xo1; }
  else                 { y = y2; meta = meta2; eas = eas2; wep = wep2; st = st2; xo = xo2; }

  __shared__ unsigned int ypk[4096];    // 16 KB: [node][j] = bf16(y[d=dbase+j]) | bf16(y[d+64])<<16
  __shared__ float agg[8192];           // 32 KB
  __shared__ unsigned int easta[8][512];// 16 KB: per-wave 64 edges x 8 dwords
  const int g = blockIdx.x >> 1;
  const int dbase = (blockIdx.x & 1) * 128;
  const int tid = threadIdx.x;

  for (int i = tid; i < 4096; i += 512) {
    int n = i >> 6, j = i & 63;
    const float* yr = y + (size_t)(g * 64 + n) * 512 + dbase + j;
    float a = yr[0], b = yr[64];
    ypk[i] = (unsigned)f2bf(a) | ((unsigned)f2bf(b) << 16);
  }
  for (int i = tid; i < 8192; i += 512) agg[i] = 0.f;

  const int l = tid & 63;
  const int d0 = dbase + l, d1 = d0 + 64;
  unsigned int we0[8], we1[8];
#pragma unroll
  for (int j = 0; j < 8; ++j) {
    we0[j] = wep[j * 256 + d0];
    we1[j] = wep[j * 256 + d1];
  }
  __syncthreads();

  const int w = tid >> 6;  // wave owns nodes [8w, 8w+8)
  const int estart = st[g * 65 + w * 8];
  const int eend   = st[g * 65 + w * 8 + 8];
  unsigned int* myea = &easta[w][0];
  float c0 = 0.f, c1 = 0.f;
  int curnd = -1;

  for (int base = estart; base < eend; base += 64) {
    int lim = eend - base;
    if (lim > 64) lim = 64;
    const int idx = base + (l < lim ? l : lim - 1);
    const size_t gi = (size_t)g * 2048 + idx;
    int mv = meta[gi];
    uint4 eA = *(const uint4*)(eas + gi * 8);
    uint4 eB = *(const uint4*)(eas + gi * 8 + 4);
    *(uint4*)(myea + l * 8) = eA;       // wave-private stage
    *(uint4*)(myea + l * 8 + 4) = eB;

    for (int j = 0; j < lim; ++j) {
      const int m = __builtin_amdgcn_readlane(mv, j);  // SGPR
      const int src = m & 63;
      const int nd = (m >> 8) & 63;
      if (nd != curnd) {  // scalar branch (m is SGPR)
        if (curnd >= 0) {
          agg[curnd * 128 + l] = c0;
          agg[curnd * 128 + l + 64] = c1;
        }
        curnd = nd;
        c0 = 0.f;
        c1 = 0.f;
      }
      unsigned int yv = ypk[src * 64 + l];
      float m0 = __builtin_bit_cast(float, yv << 16);
      float m1 = __builtin_bit_cast(float, yv & 0xFFFF0000u);
      const unsigned int* ej = myea + j * 8;
      uint4 a0 = *(const uint4*)(ej);       // broadcast ds_read_b128
      uint4 a1 = *(const uint4*)(ej + 4);
      m0 = dot2f(a0.x, we0[0], m0); m1 = dot2f(a0.x, we1[0], m1);
      m0 = dot2f(a0.y, we0[1], m0); m1 = dot2f(a0.y, we1[1], m1);
      m0 = dot2f(a0.z, we0[2], m0); m1 = dot2f(a0.z, we1[2], m1);
      m0 = dot2f(a0.w, we0[3], m0); m1 = dot2f(a0.w, we1[3], m1);
      m0 = dot2f(a1.x, we0[4], m0); m1 = dot2f(a1.x, we1[4], m1);
      m0 = dot2f(a1.y, we0[5], m0); m1 = dot2f(a1.y, we1[5], m1);
      m0 = dot2f(a1.z, we0[6], m0); m1 = dot2f(a1.z, we1[6], m1);
      m0 = dot2f(a1.w, we0[7], m0); m1 = dot2f(a1.w, we1[7], m1);
      c0 += fmaxf(m0, 0.f);
      c1 += fmaxf(m1, 0.f);
    }
  }
  if (curnd >= 0) {
    agg[curnd * 128 + l] = c0;
    agg[curnd * 128 + l + 64] = c1;
  }
  __syncthreads();
  for (int i = tid; i < 8192; i += 512) {
    int n = i >> 7, dd = i & 127;
    float v = y[(size_t)(g * 64 + n) * 512 + 256 + dbase + dd] + agg[i];
    xo[(size_t)(g * 64 + n) * 256 + dbase + dd] = fmaxf(v, 0.f);
  }
}

// ---------------------------------------------------------------------------
// dot_pool: per graph, item = X1 @ X2^T [64x64]; write max & mean to fusion.
// ---------------------------------------------------------------------------
__global__ __launch_bounds__(256) void dot_pool_k(
    const float* __restrict__ x1, const float* __restrict__ x2,
    float* __restrict__ fusion, int step)
{
  __shared__ float s1[64][68];
  __shared__ float s2[64][68];
  __shared__ float redm[4], reds[4];
  const int g = blockIdx.x;
  const int tid = threadIdx.x;
  const int ti = (tid & 15) * 4;
  const int tj = (tid >> 4) * 4;
  float acc[4][4] = {};
  for (int kc = 0; kc < 256; kc += 64) {
    for (int rr = 0; rr < 4; ++rr) {
      int lin = tid + rr * 256;
      int n = lin >> 4, k4 = (lin & 15) * 4;
      *(float4*)&s1[n][k4] = *(const float4*)(x1 + (size_t)(g * 64 + n) * 256 + kc + k4);
      *(float4*)&s2[n][k4] = *(const float4*)(x2 + (size_t)(g * 64 + n) * 256 + kc + k4);
    }
    __syncthreads();
    for (int kk = 0; kk < 64; kk += 4) {
      float4 a0 = *(const float4*)&s1[ti + 0][kk];
      float4 a1 = *(const float4*)&s1[ti + 1][kk];
      float4 a2 = *(const float4*)&s1[ti + 2][kk];
      float4 a3 = *(const float4*)&s1[ti + 3][kk];
      float4 b0 = *(const float4*)&s2[tj + 0][kk];
      float4 b1 = *(const float4*)&s2[tj + 1][kk];
      float4 b2 = *(const float4*)&s2[tj + 2][kk];
      float4 b3 = *(const float4*)&s2[tj + 3][kk];
      acc[0][0] += dot4(a0, b0); acc[0][1] += dot4(a0, b1);
      acc[0][2] += dot4(a0, b2); acc[0][3] += dot4(a0, b3);
      acc[1][0] += dot4(a1, b0); acc[1][1] += dot4(a1, b1);
      acc[1][2] += dot4(a1, b2); acc[1][3] += dot4(a1, b3);
      acc[2][0] += dot4(a2, b0); acc[2][1] += dot4(a2, b1);
      acc[2][2] += dot4(a2, b2); acc[2][3] += dot4(a2, b3);
      acc[3][0] += dot4(a3, b0); acc[3][1] += dot4(a3, b1);
      acc[3][2] += dot4(a3, b2); acc[3][3] += dot4(a3, b3);
    }
    __syncthreads();
  }
  float mymax = -1e30f, mysum = 0.f;
  for (int i = 0; i < 4; ++i)
    for (int j = 0; j < 4; ++j) {
      mymax = fmaxf(mymax, acc[i][j]);
      mysum += acc[i][j];
    }
  for (int off = 32; off; off >>= 1) {
    mymax = fmaxf(mymax, __shfl_down(mymax, off, 64));
    mysum += __shfl_down(mysum, off, 64);
  }
  if ((tid & 63) == 0) { redm[tid >> 6] = mymax; reds[tid >> 6] = mysum; }
  __syncthreads();
  if (tid == 0) {
    float gm = fmaxf(fmaxf(redm[0], redm[1]), fmaxf(redm[2], redm[3]));
    float gs = reds[0] + reds[1] + reds[2] + reds[3];
    fusion[g * 6 + step * 2] = gm;
    fusion[g * 6 + step * 2 + 1] = gs * (1.f / 4096.f);
  }
}

// ---------------------------------------------------------------------------
// readout (dual, grid 512): R[g] = [mean | sum | top3-by-last-col rows]
// ---------------------------------------------------------------------------
__global__ __launch_bounds__(256) void readout_dual(
    const float* __restrict__ xm1, const float* __restrict__ xm2,
    float* __restrict__ R1, float* __restrict__ R2)
{
  const int mol = blockIdx.x >> 8;
  const float* xm = mol ? xm2 : xm1;
  float* R = mol ? R2 : R1;
  __shared__ float lastcol[64];
  __shared__ int topi[3];
  const int g = blockIdx.x & 255, d = threadIdx.x;
  float s = 0.f;
  for (int n = 0; n < 64; ++n) s += xm[(size_t)(g * 64 + n) * 256 + d];
  R[(size_t)g * 1280 + d] = s * (1.f / 64.f);
  R[(size_t)g * 1280 + 256 + d] = s;
  if (d < 64) lastcol[d] = xm[(size_t)(g * 64 + d) * 256 + 255];
  __syncthreads();
  if (d == 0) {
    unsigned long long used = 0;
    for (int j = 0; j < 3; ++j) {
      float best = -1e30f;
      int bi = 0;
      for (int n = 0; n < 64; ++n) {
        if ((used >> n) & 1ull) continue;
        if (lastcol[n] > best) { best = lastcol[n]; bi = n; }
      }
      used |= (1ull << bi);
      topi[j] = bi;
    }
  }
  __syncthreads();
  for (int j = 0; j < 3; ++j)
    R[(size_t)g * 1280 + 512 + j * 256 + d] =
        xm[(size_t)(g * 64 + topi[j]) * 256 + d];
}

// ---------------------------------------------------------------------------
// final head: out = (cat(outm1, outm2, fusion) @ Wo1 + bo1) @ Wo2 + bo2
// ---------------------------------------------------------------------------
__global__ __launch_bounds__(256) void final_head(
    const float* __restrict__ outm1, const float* __restrict__ outm2,
    const float* __restrict__ fusion,
    const float* __restrict__ Wo1, const float* __restrict__ bo1,
    const float* __restrict__ Wo2, const float* __restrict__ bo2,
    float* __restrict__ out)
{
  __shared__ float cat[520];
  __shared__ float r0s[4], r1s[4];
  const int g = blockIdx.x, t = threadIdx.x;
  cat[t] = outm1[(size_t)g * 256 + t];
  cat[256 + t] = outm2[(size_t)g * 256 + t];
  if (t < 6) cat[512 + t] = fusion[g * 6 + t];
  __syncthreads();
  float acc = bo1[t];
  for (int k = 0; k < 518; ++k) acc = fmaf(cat[k], Wo1[(size_t)k * 256 + t], acc);
  float p0 = acc * Wo2[t * 2];
  float p1 = acc * Wo2[t * 2 + 1];
  for (int off = 32; off; off >>= 1) {
    p0 += __shfl_down(p0, off, 64);
    p1 += __shfl_down(p1, off, 64);
  }
  if ((t & 63) == 0) { r0s[t >> 6] = p0; r1s[t >> 6] = p1; }
  __syncthreads();
  if (t == 0) {
    out[g * 2] = r0s[0] + r0s[1] + r0s[2] + r0s[3] + bo2[0];
    out[g * 2 + 1] = r1s[0] + r1s[1] + r1s[2] + r1s[3] + bo2[1];
  }
}

// ---------------------------------------------------------------------------
// All weight transposes in one launch. Jobs (block ranges):
// [0,128) W0_1(K=128) | [128,256) W0_2 | [256,512) Wn1 | [512,768) Ws1 |
// [768,1024) Wn2 | [1024,1280) Ws2 | [1280,2560) Wf1(K=1280) | [2560,3840) Wf2
// ---------------------------------------------------------------------------
__global__ __launch_bounds__(256) void transpose_all(
    const float* __restrict__ W0_1, const float* __restrict__ W0_2,
    const float* __restrict__ Wn1, const float* __restrict__ Ws1,
    const float* __restrict__ Wn2, const float* __restrict__ Ws2,
    const float* __restrict__ Wf1, const float* __restrict__ Wf2,
    unsigned short* __restrict__ W0T1, unsigned short* __restrict__ W0T2,
    unsigned short* __restrict__ WcT1, unsigned short* __restrict__ WcT2,
    unsigned short* __restrict__ WfT1, unsigned short* __restrict__ WfT2)
{
  const int b = blockIdx.x, n = threadIdx.x;
  const float* src;
  unsigned short* dst;
  int k, K;
  if (b < 128)       { src = W0_1; dst = W0T1;        k = b;        K = 128; }
  else if (b < 256)  { src = W0_2; dst = W0T2;        k = b - 128;  K = 128; }
  else if (b < 512)  { src = Wn1;  dst = WcT1;        k = b - 256;  K = 256; }
  else if (b < 768)  { src = Ws1;  dst = WcT1 + 65536;k = b - 512;  K = 256; }
  else if (b < 1024) { src = Wn2;  dst = WcT2;        k = b - 768;  K = 256; }
  else if (b < 1280) { src = Ws2;  dst = WcT2 + 65536;k = b - 1024; K = 256; }
  else if (b < 2560) { src = Wf1;  dst = WfT1;        k = b - 1280; K = 1280; }
  else               { src = Wf2;  dst = WfT2;        k = b - 2560; K = 1280; }
  dst[n * K + k] = f2bf(src[(size_t)k * 256 + n]);
}

__global__ void misc_prep(
    const float* bm1, const float* bs1, const float* bm2, const float* bs2,
    const float* We1, const float* We2,
    float* bcat1, float* bcat2,
    unsigned int* weh1, unsigned int* weh2)
{
  int idx = blockIdx.x * 256 + threadIdx.x;  // grid 20 -> 5120
  if (idx < 512) {
    bcat1[idx] = idx < 256 ? bm1[idx] : bs1[idx - 256];
  } else if (idx < 1024) {
    int i = idx - 512;
    bcat2[i] = i < 256 ? bm2[i] : bs2[i - 256];
  } else if (idx < 3072) {
    int i = idx - 1024, j = i >> 8, d = i & 255;
    weh1[i] = pack_h2(We1[(2 * j) * 256 + d], We1[(2 * j + 1) * 256 + d]);
  } else if (idx < 5120) {
    int i = idx - 3072, j = i >> 8, d = i & 255;
    weh2[i] = pack_h2(We2[(2 * j) * 256 + d], We2[(2 * j + 1) * 256 + d]);
  }
}

// ---------------------------------------------------------------------------
extern "C" void kernel_launch(void* const* d_in, const int* in_sizes, int n_in,
                              void* d_out, int out_size, void* d_ws, size_t ws_size,
                              hipStream_t stream)
{
  const float* x1 = (const float*)d_in[0];
  const int* ei1 = (const int*)d_in[1];
  const float* ea1 = (const float*)d_in[2];
  const float* x2 = (const float*)d_in[4];
  const int* ei2 = (const int*)d_in[5];
  const float* ea2 = (const float*)d_in[6];
  const float* W0_1 = (const float*)d_in[8];
  const float* b0_1 = (const float*)d_in[9];
  const float* W0_2 = (const float*)d_in[10];
  const float* b0_2 = (const float*)d_in[11];
  const float* Wn1 = (const float*)d_in[12];
  const float* We1 = (const float*)d_in[13];
  const float* bm1 = (const float*)d_in[14];
  const float* Ws1 = (const float*)d_in[15];
  const float* bs1 = (const float*)d_in[16];
  const float* Wn2 = (const float*)d_in[17];
  const float* We2 = (const float*)d_in[18];
  const float* bm2 = (const float*)d_in[19];
  const float* Ws2 = (const float*)d_in[20];
  const float* bs2 = (const float*)d_in[21];
  const float* Wf1 = (const float*)d_in[22];
  const float* bf1 = (const float*)d_in[23];
  const float* Wf2 = (const float*)d_in[24];
  const float* bf2 = (const float*)d_in[25];
  const float* Wo1 = (const float*)d_in[26];
  const float* bo1 = (const float*)d_in[27];
  const float* Wo2 = (const float*)d_in[28];
  const float* bo2 = (const float*)d_in[29];
  float* out = (float*)d_out;

  float* w = (float*)d_ws;
  size_t off = 0;
  auto alloc = [&](size_t nf) { float* p = w + off; off += nf; return p; };
  float* xmA1 = alloc(4194304);
  float* xmA2 = alloc(4194304);
  float* xmB1 = alloc(4194304);
  float* xmB2 = alloc(4194304);
  float* y1 = alloc(8388608);
  float* y2 = alloc(8388608);
  float* R1 = alloc(327680);
  float* R2 = alloc(327680);
  float* outm1 = alloc(65536);
  float* outm2 = alloc(65536);
  float* fusion = alloc(1536);
  float* bcat1 = alloc(512);
  float* bcat2 = alloc(512);
  unsigned short* W0T1 = (unsigned short*)alloc(16384);
  unsigned short* W0T2 = (unsigned short*)alloc(16384);
  unsigned short* WcT1 = (unsigned short*)alloc(65536);
  unsigned short* WcT2 = (unsigned short*)alloc(65536);
  unsigned short* WfT1 = (unsigned short*)alloc(163840);
  unsigned short* WfT2 = (unsigned short*)alloc(163840);
  unsigned int* weh1 = (unsigned int*)alloc(2048);
  unsigned int* weh2 = (unsigned int*)alloc(2048);
  unsigned int* eah1 = (unsigned int*)alloc(4194304);
  unsigned int* eah2 = (unsigned int*)alloc(4194304);
  int* meta1 = (int*)alloc(524288);
  int* meta2 = (int*)alloc(524288);
  int* perm1 = (int*)alloc(524288);
  int* perm2 = (int*)alloc(524288);
  int* starts1 = (int*)alloc(16640);
  int* starts2 = (int*)alloc(16640);
  (void)in_sizes; (void)n_in; (void)out_size; (void)ws_size;

  // ---- prep ----
  sort_edges_dual<<<512, 256, 0, stream>>>(ei1, ei2, meta1, meta2,
                                           perm1, perm2, starts1, starts2);
  transpose_all<<<3840, 256, 0, stream>>>(W0_1, W0_2, Wn1, Ws1, Wn2, Ws2,
                                          Wf1, Wf2, W0T1, W0T2, WcT1, WcT2,
                                          WfT1, WfT2);
  misc_prep<<<20, 256, 0, stream>>>(bm1, bs1, bm2, bs2, We1, We2,
                                    bcat1, bcat2, weh1, weh2);
  ea_gather_pack_dual<<<4096, 256, 0, stream>>>(ea1, ea2, perm1, perm2,
                                                eah1, eah2);

  // ---- embed: xm = rrelu(x @ W0 + b0) ----
  gemm_bf16_dual<<<dim3(128, 2, 2), 256, 0, stream>>>(
      x1, W0T1, b0_1, xmA1, x2, W0T2, b0_2, xmA2, 128, 256, 128, 2);

  // ---- 3 message-passing steps ----
  float* cur1 = xmA1; float* cur2 = xmA2;
  float* nxt1 = xmB1; float* nxt2 = xmB2;
  for (int step = 0; step < 3; ++step) {
    gemm_bf16_dual<<<dim3(128, 4, 2), 256, 0, stream>>>(
        cur1, WcT1, bcat1, y1, cur2, WcT2, bcat2, y2, 256, 512, 256, 0);
    edge_conv_dual<<<dim3(512, 1, 2), 512, 0, stream>>>(
        y1, meta1, eah1, weh1, starts1, nxt1,
        y2, meta2, eah2, weh2, starts2, nxt2);
    dot_pool_k<<<256, 256, 0, stream>>>(nxt1, nxt2, fusion, step);
    float* t1 = cur1; cur1 = nxt1; nxt1 = t1;
    float* t2 = cur2; cur2 = nxt2; nxt2 = t2;
  }

  // ---- readout + head ----
  readout_dual<<<512, 256, 0, stream>>>(cur1, cur2, R1, R2);
  gemm_bf16_dual<<<dim3(2, 2, 2), 256, 0, stream>>>(
      R1, WfT1, bf1, outm1, R2, WfT2, bf2, outm2, 1280, 256, 1280, 0);
  final_head<<<256, 256, 0, stream>>>(outm1, outm2, fusion,
                                      Wo1, bo1, Wo2, bo2, out);
}